// Round 1
// baseline (2839.971 us; speedup 1.0000x reference)
//
#include <hip/hip_runtime.h>
#include <math.h>

#define NN 200000
#define NE 500000
#define FF 166
#define HH 128
#define CC 2
#define TT 49
#define GG 498            // 3*FF
#define WSZ (FF*FF)       // 27556
#define PADN 203136       // max padded rows: <= NN + 49*63 rounded to tiles
#define MAXTILES 3200

// ---------------- prep: transpose weights for coalesced K-major access ----------------
__global__ void prep_transpose(const float* __restrict__ wih, const float* __restrict__ whh,
                               const float* __restrict__ projw,
                               float* __restrict__ wihT, float* __restrict__ whhT,
                               float* __restrict__ projwT) {
    int idx = blockIdx.x * 256 + threadIdx.x;
    const int A = GG * FF; // 82668
    if (idx < A) {
        int c = idx / FF, k = idx % FF;
        wihT[k * GG + c] = wih[idx];
    } else if (idx < 2 * A) {
        int q = idx - A;
        int c = q / FF, k = q % FF;
        whhT[k * GG + c] = whh[q];
    } else if (idx < 2 * A + HH * FF) {
        int q = idx - 2 * A;
        int h = q / FF, k = q % FF;
        projwT[k * HH + h] = projw[q];
    }
}

// ---------------- CSR build ----------------
__global__ void count_indeg(const int* __restrict__ dst, int* __restrict__ off) {
    int e = blockIdx.x * 256 + threadIdx.x;
    if (e < NE) atomicAdd(&off[dst[e]], 1);
}

__global__ void count_bucket(const int* __restrict__ ts, int* __restrict__ bcnt) {
    int i = blockIdx.x * 256 + threadIdx.x;
    if (i < NN) atomicAdd(&bcnt[ts[i]], 1);
}

__global__ __launch_bounds__(1024) void scan_offsets(int* __restrict__ off) {
    // in-place exclusive scan of off[0..NN), then off[NN] = total
    __shared__ int s[1024];
    int tid = threadIdx.x;
    const int CH = (NN + 1023) / 1024; // 196
    int begin = tid * CH;
    int end = begin + CH; if (end > NN) end = NN;
    int sum = 0;
    for (int j = begin; j < end; ++j) sum += off[j];
    s[tid] = sum;
    __syncthreads();
    for (int d = 1; d < 1024; d <<= 1) {
        int v = (tid >= d) ? s[tid - d] : 0;
        __syncthreads();
        s[tid] += v;
        __syncthreads();
    }
    int run = (tid == 0) ? 0 : s[tid - 1];
    for (int j = begin; j < end; ++j) {
        int v = off[j];
        off[j] = run;
        run += v;
    }
    if (tid == 1023) off[NN] = s[1023];
}

__global__ void fill_adj(const int* __restrict__ src, const int* __restrict__ dst,
                         const int* __restrict__ off, int* __restrict__ cursor,
                         int* __restrict__ adjsrc) {
    int e = blockIdx.x * 256 + threadIdx.x;
    if (e < NE) {
        int d = dst[e];
        int p = atomicAdd(&cursor[d], 1);
        adjsrc[off[d] + p] = src[e];
    }
}

// degf[v][t] = 1 + #{in-edges (k->v) : ts[k] <= t}  (as float)
__global__ void degf_k(const int* __restrict__ off, const int* __restrict__ adjsrc,
                       const int* __restrict__ ts, float* __restrict__ degf) {
    int i = blockIdx.x * 256 + threadIdx.x;
    if (i >= NN) return;
    int e0 = off[i], e1 = off[i + 1];
    for (int t = 0; t < TT; ++t) {
        int c = 1;
        for (int e = e0; e < e1; ++e) c += (ts[adjsrc[e]] <= t) ? 1 : 0;
        degf[(size_t)i * TT + t] = (float)c;
    }
}

// ---------------- bucket / tile tables ----------------
__global__ void make_tiles(const int* __restrict__ bcnt, int* __restrict__ pstart,
                           int* __restrict__ tile_t, int* __restrict__ tile_r0,
                           int* __restrict__ meta) {
    if (threadIdx.x == 0 && blockIdx.x == 0) {
        int p = 0, nt = 0;
        for (int t = 0; t < TT; ++t) {
            pstart[t] = p;
            int c = bcnt[t];
            int ntile = (c + 63) / 64;
            for (int u = 0; u < ntile; ++u) {
                tile_t[nt] = t;
                tile_r0[nt] = p + u * 64;
                nt++;
            }
            p += ntile * 64;
        }
        pstart[TT] = p;
        meta[0] = nt;
        meta[1] = p;
    }
}

__global__ void perm_fill(const int* __restrict__ ts, const int* __restrict__ pstart,
                          int* __restrict__ bcur, int* __restrict__ perm) {
    int i = blockIdx.x * 256 + threadIdx.x;
    if (i < NN) {
        int t = ts[i];
        int p = atomicAdd(&bcur[t], 1);
        perm[pstart[t] + p] = i;
    }
}

// ---------------- GRU weight evolution: one step ----------------
__global__ __launch_bounds__(256) void gru_step(const float* __restrict__ Ws, float* __restrict__ Wd,
                                                const float* __restrict__ wihT, const float* __restrict__ whhT,
                                                const float* __restrict__ bih, const float* __restrict__ bhh) {
    int g = blockIdx.x * 256 + threadIdx.x;
    if (g >= WSZ) return;
    int r = g / FF, c = g % FF;
    const float* wr = Ws + (size_t)r * FF;
    float a0 = bih[c], a1 = bih[FF + c], a2 = bih[2 * FF + c];
    float b0 = bhh[c], b1 = bhh[FF + c], b2 = bhh[2 * FF + c];
    for (int k = 0; k < FF; ++k) {
        float wv = wr[k];
        const float* ik = wihT + (size_t)k * GG;
        const float* hk = whhT + (size_t)k * GG;
        a0 += wv * ik[c];
        a1 += wv * ik[FF + c];
        a2 += wv * ik[2 * FF + c];
        b0 += wv * hk[c];
        b1 += wv * hk[FF + c];
        b2 += wv * hk[2 * FF + c];
    }
    float rg = 1.0f / (1.0f + expf(-(a0 + b0)));
    float zg = 1.0f / (1.0f + expf(-(a1 + b1)));
    float ng = tanhf(a2 + rg * b2);
    Wd[g] = (1.0f - zg) * ng + zg * Ws[g];
}

// ---------------- y build: y_i = x_i/deg_i + sum norm_ij x_j ----------------
__global__ __launch_bounds__(256) void ybuild(const int* __restrict__ perm, const int* __restrict__ ts,
                                              const float* __restrict__ x,
                                              const int* __restrict__ off, const int* __restrict__ adjsrc,
                                              const float* __restrict__ degf, float* __restrict__ Yb) {
    int r = blockIdx.x * 4 + (threadIdx.x >> 6);
    int lane = threadIdx.x & 63;
    int i = perm[r];
    if (i < 0) return;
    int t = ts[i];
    float degi = degf[(size_t)i * TT + t];
    float inv_degi = 1.0f / degi;
    float dinv_i = rsqrtf(degi);
    int f1 = lane + 64, f2 = lane + 128;
    const float* xi = x + (size_t)i * FF;
    float a0 = xi[lane] * inv_degi;
    float a1 = xi[f1] * inv_degi;
    float a2 = (f2 < FF) ? xi[f2] * inv_degi : 0.0f;
    int e0 = off[i], e1 = off[i + 1];
    for (int e = e0; e < e1; ++e) {
        int j = adjsrc[e];
        if (ts[j] <= t) {
            float nrm = rsqrtf(degf[(size_t)j * TT + t]) * dinv_i;
            const float* xj = x + (size_t)j * FF;
            a0 += nrm * xj[lane];
            a1 += nrm * xj[f1];
            if (f2 < FF) a2 += nrm * xj[f2];
        }
    }
    float* yr = Yb + (size_t)r * FF;
    yr[lane] = a0;
    yr[f1] = a1;
    if (f2 < FF) yr[f2] = a2;
}

// ---------------- fused AGG = Y@W_t, Z = relu(AGG@projT+b), logits = Z@clsT+b ----------------
__global__ __launch_bounds__(256) void gemm_fused(const int* __restrict__ meta,
                                                  const int* __restrict__ tile_t, const int* __restrict__ tile_r0,
                                                  const int* __restrict__ perm,
                                                  const float* __restrict__ Yb, const float* __restrict__ W_all,
                                                  const float* __restrict__ projwT,
                                                  const float* __restrict__ proj_b,
                                                  const float* __restrict__ cls_w, const float* __restrict__ cls_b,
                                                  float* __restrict__ out) {
    __shared__ float sm[64 * FF];
    int w = blockIdx.x;
    if (w >= meta[0]) return;
    int t = tile_t[w], r0 = tile_r0[w];
    int tid = threadIdx.x;

    // stage Y tile (64 x 166)
    for (int idx = tid; idx < 64 * FF; idx += 256)
        sm[idx] = Yb[(size_t)(r0 + idx / FF) * FF + (idx % FF)];
    __syncthreads();

    int a = tid & 15;   // column group
    int b = tid >> 4;   // row group: rows b*4 .. b*4+3
    const float* W = W_all + (size_t)t * WSZ;

    // phase 1: AGG = Y @ W_t
    float acc[4][11];
    #pragma unroll
    for (int rr = 0; rr < 4; ++rr)
        #pragma unroll
        for (int j = 0; j < 11; ++j) acc[rr][j] = 0.0f;

    for (int k = 0; k < FF; ++k) {
        float y0 = sm[(b * 4 + 0) * FF + k];
        float y1 = sm[(b * 4 + 1) * FF + k];
        float y2 = sm[(b * 4 + 2) * FF + k];
        float y3 = sm[(b * 4 + 3) * FF + k];
        const float* wk = W + (size_t)k * FF;
        #pragma unroll
        for (int j = 0; j < 11; ++j) {
            int c = a + 16 * j;
            if (c < FF) {
                float wv = wk[c];
                acc[0][j] += y0 * wv;
                acc[1][j] += y1 * wv;
                acc[2][j] += y2 * wv;
                acc[3][j] += y3 * wv;
            }
        }
    }
    __syncthreads();
    #pragma unroll
    for (int rr = 0; rr < 4; ++rr)
        #pragma unroll
        for (int j = 0; j < 11; ++j) {
            int c = a + 16 * j;
            if (c < FF) sm[(b * 4 + rr) * FF + c] = acc[rr][j];
        }
    __syncthreads();

    // phase 2: Z = relu(AGG @ projwT + proj_b)
    float z[4][8];
    #pragma unroll
    for (int rr = 0; rr < 4; ++rr)
        #pragma unroll
        for (int jj = 0; jj < 8; ++jj) z[rr][jj] = 0.0f;

    for (int k = 0; k < FF; ++k) {
        float y0 = sm[(b * 4 + 0) * FF + k];
        float y1 = sm[(b * 4 + 1) * FF + k];
        float y2 = sm[(b * 4 + 2) * FF + k];
        float y3 = sm[(b * 4 + 3) * FF + k];
        const float* pk = projwT + (size_t)k * HH;
        #pragma unroll
        for (int jj = 0; jj < 8; ++jj) {
            int h = a + 16 * jj;
            float pv = pk[h];
            z[0][jj] += y0 * pv;
            z[1][jj] += y1 * pv;
            z[2][jj] += y2 * pv;
            z[3][jj] += y3 * pv;
        }
    }
    __syncthreads();
    #pragma unroll
    for (int rr = 0; rr < 4; ++rr)
        #pragma unroll
        for (int jj = 0; jj < 8; ++jj) {
            int h = a + 16 * jj;
            sm[(b * 4 + rr) * HH + h] = fmaxf(z[rr][jj] + proj_b[h], 0.0f);
        }
    __syncthreads();

    // phase 3: logits
    if (tid < 128) {
        int row = tid >> 1, c = tid & 1;
        const float* zr = sm + row * HH;
        const float* cw = cls_w + c * HH;
        float s = 0.0f;
        for (int h = 0; h < HH; ++h) s += zr[h] * cw[h];
        int node = perm[r0 + row];
        if (node >= 0) out[(size_t)node * CC + c] = s + cls_b[c];
    }
}

// ---------------- host ----------------
extern "C" void kernel_launch(void* const* d_in, const int* in_sizes, int n_in,
                              void* d_out, int out_size, void* d_ws, size_t ws_size,
                              hipStream_t stream) {
    const float* x = (const float*)d_in[0];
    const int* ei = (const int*)d_in[1];
    const int* srcp = ei;
    const int* dstp = ei + NE;
    const int* ts = (const int*)d_in[2];
    const float* initial_w = (const float*)d_in[3];
    const float* wih = (const float*)d_in[4];
    const float* whh = (const float*)d_in[5];
    const float* bih = (const float*)d_in[6];
    const float* bhh = (const float*)d_in[7];
    const float* projw = (const float*)d_in[8];
    const float* projb = (const float*)d_in[9];
    const float* clsw = (const float*)d_in[10];
    const float* clsb = (const float*)d_in[11];
    float* out = (float*)d_out;

    char* base = (char*)d_ws;
    size_t o = 0;
    auto alloc = [&](size_t bytes) { size_t r = o; o = (o + bytes + 255) & ~(size_t)255; return r; };

    float* W_all  = (float*)(base + alloc((size_t)TT * WSZ * 4));
    float* wihT   = (float*)(base + alloc((size_t)FF * GG * 4));
    float* whhT   = (float*)(base + alloc((size_t)FF * GG * 4));
    float* projwT = (float*)(base + alloc((size_t)FF * HH * 4));
    int*   off    = (int*)  (base + alloc((size_t)(NN + 1) * 4));
    int*   cursor = (int*)  (base + alloc((size_t)NN * 4));
    int*   adjsrc = (int*)  (base + alloc((size_t)NE * 4));
    float* degf   = (float*)(base + alloc((size_t)NN * TT * 4));
    int*   bcnt   = (int*)  (base + alloc((size_t)TT * 4));
    int*   bcur   = (int*)  (base + alloc((size_t)TT * 4));
    int*   pstart = (int*)  (base + alloc((size_t)(TT + 1) * 4));
    int*   meta   = (int*)  (base + alloc(2 * 4));
    int*   tile_t = (int*)  (base + alloc((size_t)MAXTILES * 4));
    int*   tile_r0= (int*)  (base + alloc((size_t)MAXTILES * 4));
    int*   perm   = (int*)  (base + alloc((size_t)PADN * 4));
    float* Yb     = (float*)(base + alloc((size_t)PADN * FF * 4));

    hipMemsetAsync(off, 0, (size_t)(NN + 1) * 4, stream);
    hipMemsetAsync(cursor, 0, (size_t)NN * 4, stream);
    hipMemsetAsync(bcnt, 0, (size_t)TT * 4, stream);
    hipMemsetAsync(bcur, 0, (size_t)TT * 4, stream);
    hipMemsetAsync(perm, 0xFF, (size_t)PADN * 4, stream);

    prep_transpose<<<729, 256, 0, stream>>>(wih, whh, projw, wihT, whhT, projwT);
    count_indeg<<<(NE + 255) / 256, 256, 0, stream>>>(dstp, off);
    count_bucket<<<(NN + 255) / 256, 256, 0, stream>>>(ts, bcnt);
    scan_offsets<<<1, 1024, 0, stream>>>(off);
    fill_adj<<<(NE + 255) / 256, 256, 0, stream>>>(srcp, dstp, off, cursor, adjsrc);
    degf_k<<<(NN + 255) / 256, 256, 0, stream>>>(off, adjsrc, ts, degf);
    make_tiles<<<1, 64, 0, stream>>>(bcnt, pstart, tile_t, tile_r0, meta);
    perm_fill<<<(NN + 255) / 256, 256, 0, stream>>>(ts, pstart, bcur, perm);

    for (int t = 0; t < TT; ++t) {
        const float* Wsrc = (t == 0) ? initial_w : (W_all + (size_t)(t - 1) * WSZ);
        gru_step<<<108, 256, 0, stream>>>(Wsrc, W_all + (size_t)t * WSZ, wihT, whhT, bih, bhh);
    }

    ybuild<<<PADN / 4, 256, 0, stream>>>(perm, ts, x, off, adjsrc, degf, Yb);

    gemm_fused<<<3174, 256, 0, stream>>>(meta, tile_t, tile_r0, perm, Yb, W_all,
                                         projwT, projb, clsw, clsb, out);
}

// Round 2
// 2522.234 us; speedup vs baseline: 1.1260x; 1.1260x over previous
//
#include <hip/hip_runtime.h>
#include <math.h>

#define NN 200000
#define NE 500000
#define FF 166
#define HH 128
#define CC 2
#define TT 49
#define GG 498            // 3*FF
#define MROW (FF*HH)      // 21248 floats per M_t
#define PADN 203136
#define MAXTILES 6400

// ---------------- prep: transpose weights for coalesced K-major access ----------------
__global__ void prep_transpose(const float* __restrict__ wih, const float* __restrict__ whh,
                               const float* __restrict__ projw,
                               float* __restrict__ wihT, float* __restrict__ whhT,
                               float* __restrict__ projwT) {
    int idx = blockIdx.x * 256 + threadIdx.x;
    const int A = GG * FF; // 82668
    if (idx < A) {
        int c = idx / FF, k = idx % FF;
        wihT[k * GG + c] = wih[idx];
    } else if (idx < 2 * A) {
        int q = idx - A;
        int c = q / FF, k = q % FF;
        whhT[k * GG + c] = whh[q];
    } else if (idx < 2 * A + HH * FF) {
        int q = idx - 2 * A;
        int h = q / FF, k = q % FF;
        projwT[k * HH + h] = projw[q];
    }
}

// ---------------- CSR build ----------------
__global__ void count_indeg(const int* __restrict__ dst, int* __restrict__ off) {
    int e = blockIdx.x * 256 + threadIdx.x;
    if (e < NE) atomicAdd(&off[dst[e]], 1);
}

__global__ void count_bucket(const int* __restrict__ ts, int* __restrict__ bcnt) {
    int i = blockIdx.x * 256 + threadIdx.x;
    if (i < NN) atomicAdd(&bcnt[ts[i]], 1);
}

__global__ __launch_bounds__(1024) void scan_offsets(int* __restrict__ off) {
    __shared__ int s[1024];
    int tid = threadIdx.x;
    const int CH = (NN + 1023) / 1024; // 196
    int begin = tid * CH;
    int end = begin + CH; if (end > NN) end = NN;
    int sum = 0;
    for (int j = begin; j < end; ++j) sum += off[j];
    s[tid] = sum;
    __syncthreads();
    for (int d = 1; d < 1024; d <<= 1) {
        int v = (tid >= d) ? s[tid - d] : 0;
        __syncthreads();
        s[tid] += v;
        __syncthreads();
    }
    int run = (tid == 0) ? 0 : s[tid - 1];
    for (int j = begin; j < end; ++j) {
        int v = off[j];
        off[j] = run;
        run += v;
    }
    if (tid == 1023) off[NN] = s[1023];
}

__global__ void fill_adj(const int* __restrict__ src, const int* __restrict__ dst,
                         const int* __restrict__ off, int* __restrict__ cursor,
                         int* __restrict__ adjsrc) {
    int e = blockIdx.x * 256 + threadIdx.x;
    if (e < NE) {
        int d = dst[e];
        int p = atomicAdd(&cursor[d], 1);
        adjsrc[off[d] + p] = src[e];
    }
}

// degf[v][t] = 1 + #{in-edges (k->v) : ts[k] <= t}
__global__ void degf_k(const int* __restrict__ off, const int* __restrict__ adjsrc,
                       const int* __restrict__ ts, float* __restrict__ degf) {
    int i = blockIdx.x * 256 + threadIdx.x;
    if (i >= NN) return;
    int e0 = off[i], e1 = off[i + 1];
    for (int t = 0; t < TT; ++t) {
        int c = 1;
        for (int e = e0; e < e1; ++e) c += (ts[adjsrc[e]] <= t) ? 1 : 0;
        degf[(size_t)i * TT + t] = (float)c;
    }
}

// ---------------- bucket / tile tables (32-row tiles, parallel) ----------------
__global__ void make_tiles(const int* __restrict__ bcnt, int* __restrict__ pstart,
                           int* __restrict__ tile_t, int* __restrict__ tile_r0,
                           int* __restrict__ meta) {
    __shared__ int s_nt[64];
    int t = threadIdx.x; // 64 threads
    int nt = (t < TT) ? (bcnt[t] + 31) / 32 : 0;
    s_nt[t] = nt;
    __syncthreads();
    for (int d = 1; d < 64; d <<= 1) {
        int v = (t >= d) ? s_nt[t - d] : 0;
        __syncthreads();
        s_nt[t] += v;
        __syncthreads();
    }
    int ntbase = s_nt[t] - nt;
    int pbase = ntbase * 32;
    if (t < TT) {
        pstart[t] = pbase;
        for (int u = 0; u < nt; ++u) {
            tile_t[ntbase + u] = t;
            tile_r0[ntbase + u] = pbase + u * 32;
        }
    }
    if (t == 63) {
        meta[0] = s_nt[63];
        meta[1] = s_nt[63] * 32;
        pstart[TT] = s_nt[63] * 32;
    }
}

__global__ void perm_fill(const int* __restrict__ ts, const int* __restrict__ pstart,
                          int* __restrict__ bcur, int* __restrict__ perm) {
    int i = blockIdx.x * 256 + threadIdx.x;
    if (i < NN) {
        int t = ts[i];
        int p = atomicAdd(&bcur[t], 1);
        perm[pstart[t] + p] = i;
    }
}

// ---------------- GRU: entire 49-step chain, rows independent ----------------
// Block b owns W rows {2b, 2b+1}; evolves them in LDS through all T steps and
// emits M_t[row,:] = W_t[row,:] @ projw^T per step. W never hits global memory.
__global__ __launch_bounds__(1024) void gru_evolve(
        const float* __restrict__ initial_w,
        const float* __restrict__ wihT, const float* __restrict__ whhT,
        const float* __restrict__ bih, const float* __restrict__ bhh,
        const float* __restrict__ projwT, float* __restrict__ M_all) {
    __shared__ float s_w[2][FF];
    __shared__ float s_a[2][GG];
    __shared__ float s_b[2][GG];
    int tid = threadIdx.x;
    int r0 = blockIdx.x * 2;

    for (int idx = tid; idx < 2 * FF; idx += 1024)
        s_w[idx / FF][idx % FF] = initial_w[(size_t)(r0 + idx / FF) * FF + idx % FF];
    __syncthreads();

    int rr = tid >> 9;      // 0..1 (row within block)
    int c  = tid & 511;     // 0..511, active when < 498
    float a_init = 0.0f, b_init = 0.0f;
    if (c < GG) { a_init = bih[c]; b_init = bhh[c]; }

    int gr = tid / FF;      // gate-combine indices (tid < 332)
    int gc = tid - gr * FF;
    int mr = tid >> 7;      // M-row indices (tid < 256)
    int mh = tid & 127;

    for (int t = 0; t < TT; ++t) {
        if (c < GG) {
            float a = a_init, b = b_init;
            const float* wr = s_w[rr];
            const float* pih = wihT + c;
            const float* phh = whhT + c;
            #pragma unroll 4
            for (int k = 0; k < FF; ++k) {
                float wv = wr[k];
                a += wv * pih[(size_t)k * GG];
                b += wv * phh[(size_t)k * GG];
            }
            s_a[rr][c] = a;
            s_b[rr][c] = b;
        }
        __syncthreads();   // S1: a/b ready
        if (tid < 2 * FF) {
            float i_r = s_a[gr][gc],          h_r = s_b[gr][gc];
            float i_z = s_a[gr][FF + gc],     h_z = s_b[gr][FF + gc];
            float i_n = s_a[gr][2 * FF + gc], h_n = s_b[gr][2 * FF + gc];
            float rg = 1.0f / (1.0f + expf(-(i_r + h_r)));
            float zg = 1.0f / (1.0f + expf(-(i_z + h_z)));
            float ng = tanhf(i_n + rg * h_n);
            s_w[gr][gc] = (1.0f - zg) * ng + zg * s_w[gr][gc];
        }
        __syncthreads();   // S2: new W rows ready
        if (tid < 256) {
            const float* wr = s_w[mr];
            float acc = 0.0f;
            #pragma unroll 4
            for (int k = 0; k < FF; ++k)
                acc += wr[k] * projwT[(size_t)k * HH + mh];
            M_all[((size_t)t * FF + r0 + mr) * HH + mh] = acc;
        }
        // no sync needed here: next iteration only reads s_w (stable since S2)
        // and writes s_a/s_b whose readers finished before S2.
    }
}

// ---------------- y build: y_i = x_i/deg_i + sum norm_ij x_j ----------------
__global__ __launch_bounds__(256) void ybuild(const int* __restrict__ perm, const int* __restrict__ ts,
                                              const float* __restrict__ x,
                                              const int* __restrict__ off, const int* __restrict__ adjsrc,
                                              const float* __restrict__ degf, float* __restrict__ Yb) {
    int r = blockIdx.x * 4 + (threadIdx.x >> 6);
    int lane = threadIdx.x & 63;
    int i = perm[r];
    if (i < 0) return;
    int t = ts[i];
    float degi = degf[(size_t)i * TT + t];
    float inv_degi = 1.0f / degi;
    float dinv_i = rsqrtf(degi);
    int f1 = lane + 64, f2 = lane + 128;
    const float* xi = x + (size_t)i * FF;
    float a0 = xi[lane] * inv_degi;
    float a1 = xi[f1] * inv_degi;
    float a2 = (f2 < FF) ? xi[f2] * inv_degi : 0.0f;
    int e0 = off[i], e1 = off[i + 1];
    for (int e = e0; e < e1; ++e) {
        int j = adjsrc[e];
        if (ts[j] <= t) {
            float nrm = rsqrtf(degf[(size_t)j * TT + t]) * dinv_i;
            const float* xj = x + (size_t)j * FF;
            a0 += nrm * xj[lane];
            a1 += nrm * xj[f1];
            if (f2 < FF) a2 += nrm * xj[f2];
        }
    }
    float* yr = Yb + (size_t)r * FF;
    yr[lane] = a0;
    yr[f1] = a1;
    if (f2 < FF) yr[f2] = a2;
}

// ---------------- fused: P = relu(Y@M_t + proj_b); logits = P@cls^T + cls_b ----------------
__global__ __launch_bounds__(256) void gemm_fused(const int* __restrict__ meta,
                                                  const int* __restrict__ tile_t, const int* __restrict__ tile_r0,
                                                  const int* __restrict__ perm,
                                                  const float* __restrict__ Yb, const float* __restrict__ M_all,
                                                  const float* __restrict__ proj_b,
                                                  const float* __restrict__ cls_w, const float* __restrict__ cls_b,
                                                  float* __restrict__ out) {
    __shared__ float sm[32 * 167];
    int w = blockIdx.x;
    if (w >= meta[0]) return;
    int t = tile_t[w], r0 = tile_r0[w];
    int tid = threadIdx.x;

    // stage Y tile (32 x 166), padded stride 167
    for (int idx = tid; idx < 32 * FF; idx += 256) {
        int row = idx / FF, col = idx - row * FF;
        sm[row * 167 + col] = Yb[(size_t)(r0 + row) * FF + col];
    }
    __syncthreads();

    int rg = tid >> 5;   // 0..7 -> rows rg*4 .. rg*4+3
    int cl = tid & 31;   // cols cl + 32*jj
    const float* M = M_all + (size_t)t * MROW;

    float acc[4][4];
    #pragma unroll
    for (int i = 0; i < 4; ++i)
        #pragma unroll
        for (int jj = 0; jj < 4; ++jj) acc[i][jj] = proj_b[cl + 32 * jj];

    #pragma unroll 2
    for (int k = 0; k < FF; ++k) {
        float y0 = sm[(rg * 4 + 0) * 167 + k];
        float y1 = sm[(rg * 4 + 1) * 167 + k];
        float y2 = sm[(rg * 4 + 2) * 167 + k];
        float y3 = sm[(rg * 4 + 3) * 167 + k];
        const float* mk = M + (size_t)k * HH;
        float m0 = mk[cl];
        float m1 = mk[cl + 32];
        float m2 = mk[cl + 64];
        float m3 = mk[cl + 96];
        acc[0][0] += y0 * m0; acc[0][1] += y0 * m1; acc[0][2] += y0 * m2; acc[0][3] += y0 * m3;
        acc[1][0] += y1 * m0; acc[1][1] += y1 * m1; acc[1][2] += y1 * m2; acc[1][3] += y1 * m3;
        acc[2][0] += y2 * m0; acc[2][1] += y2 * m1; acc[2][2] += y2 * m2; acc[2][3] += y2 * m3;
        acc[3][0] += y3 * m0; acc[3][1] += y3 * m1; acc[3][2] += y3 * m2; acc[3][3] += y3 * m3;
    }
    __syncthreads();

    // write relu'd P (32 x 128), stride 130
    #pragma unroll
    for (int i = 0; i < 4; ++i)
        #pragma unroll
        for (int jj = 0; jj < 4; ++jj)
            sm[(rg * 4 + i) * 130 + cl + 32 * jj] = fmaxf(acc[i][jj], 0.0f);
    __syncthreads();

    // logits
    if (tid < 64) {
        int row = tid >> 1, cc = tid & 1;
        const float* pr = sm + row * 130;
        const float* cw = cls_w + cc * HH;
        float s = cls_b[cc];
        #pragma unroll 4
        for (int h = 0; h < HH; ++h) s += pr[h] * cw[h];
        int node = perm[r0 + row];
        if (node >= 0) out[(size_t)node * CC + cc] = s;
    }
}

// ---------------- host ----------------
extern "C" void kernel_launch(void* const* d_in, const int* in_sizes, int n_in,
                              void* d_out, int out_size, void* d_ws, size_t ws_size,
                              hipStream_t stream) {
    const float* x = (const float*)d_in[0];
    const int* ei = (const int*)d_in[1];
    const int* srcp = ei;
    const int* dstp = ei + NE;
    const int* ts = (const int*)d_in[2];
    const float* initial_w = (const float*)d_in[3];
    const float* wih = (const float*)d_in[4];
    const float* whh = (const float*)d_in[5];
    const float* bih = (const float*)d_in[6];
    const float* bhh = (const float*)d_in[7];
    const float* projw = (const float*)d_in[8];
    const float* projb = (const float*)d_in[9];
    const float* clsw = (const float*)d_in[10];
    const float* clsb = (const float*)d_in[11];
    float* out = (float*)d_out;

    char* base = (char*)d_ws;
    size_t o = 0;
    auto alloc = [&](size_t bytes) { size_t r = o; o = (o + bytes + 255) & ~(size_t)255; return r; };

    float* M_all  = (float*)(base + alloc((size_t)TT * MROW * 4));
    float* wihT   = (float*)(base + alloc((size_t)FF * GG * 4));
    float* whhT   = (float*)(base + alloc((size_t)FF * GG * 4));
    float* projwT = (float*)(base + alloc((size_t)FF * HH * 4));
    int*   off    = (int*)  (base + alloc((size_t)(NN + 1) * 4));
    int*   cursor = (int*)  (base + alloc((size_t)NN * 4));
    int*   adjsrc = (int*)  (base + alloc((size_t)NE * 4));
    float* degf   = (float*)(base + alloc((size_t)NN * TT * 4));
    int*   bcnt   = (int*)  (base + alloc((size_t)TT * 4));
    int*   bcur   = (int*)  (base + alloc((size_t)TT * 4));
    int*   pstart = (int*)  (base + alloc((size_t)(TT + 1) * 4));
    int*   meta   = (int*)  (base + alloc(2 * 4));
    int*   tile_t = (int*)  (base + alloc((size_t)MAXTILES * 4));
    int*   tile_r0= (int*)  (base + alloc((size_t)MAXTILES * 4));
    int*   perm   = (int*)  (base + alloc((size_t)PADN * 4));
    float* Yb     = (float*)(base + alloc((size_t)PADN * FF * 4));

    hipMemsetAsync(off, 0, (size_t)(NN + 1) * 4, stream);
    hipMemsetAsync(cursor, 0, (size_t)NN * 4, stream);
    hipMemsetAsync(bcnt, 0, (size_t)TT * 4, stream);
    hipMemsetAsync(bcur, 0, (size_t)TT * 4, stream);
    hipMemsetAsync(perm, 0xFF, (size_t)PADN * 4, stream);

    prep_transpose<<<729, 256, 0, stream>>>(wih, whh, projw, wihT, whhT, projwT);
    count_indeg<<<(NE + 255) / 256, 256, 0, stream>>>(dstp, off);
    count_bucket<<<(NN + 255) / 256, 256, 0, stream>>>(ts, bcnt);
    scan_offsets<<<1, 1024, 0, stream>>>(off);
    fill_adj<<<(NE + 255) / 256, 256, 0, stream>>>(srcp, dstp, off, cursor, adjsrc);
    degf_k<<<(NN + 255) / 256, 256, 0, stream>>>(off, adjsrc, ts, degf);
    make_tiles<<<1, 64, 0, stream>>>(bcnt, pstart, tile_t, tile_r0, meta);
    perm_fill<<<(NN + 255) / 256, 256, 0, stream>>>(ts, pstart, bcur, perm);

    gru_evolve<<<83, 1024, 0, stream>>>(initial_w, wihT, whhT, bih, bhh, projwT, M_all);

    ybuild<<<PADN / 4, 256, 0, stream>>>(perm, ts, x, off, adjsrc, degf, Yb);

    gemm_fused<<<MAXTILES, 256, 0, stream>>>(meta, tile_t, tile_r0, perm, Yb, M_all,
                                             projb, clsw, clsb, out);
}

// Round 3
// 1663.648 us; speedup vs baseline: 1.7071x; 1.5161x over previous
//
#include <hip/hip_runtime.h>
#include <hip/hip_fp16.h>
#include <math.h>

#define NN 200000
#define NE 500000
#define FF 166
#define HH 128
#define CC 2
#define TT 49
#define GG 498            // 3*FF
#define PADN 203136
#define MAXTILES 6400

// ---------------- prep: transposed fp16 GRU weights ([k][512] padded), fp32 projT ----------------
__global__ void prep_transpose(const float* __restrict__ wih, const float* __restrict__ whh,
                               const float* __restrict__ projw,
                               __half* __restrict__ wihT16, __half* __restrict__ whhT16,
                               float* __restrict__ projwT) {
    int idx = blockIdx.x * 256 + threadIdx.x;
    const int A = FF * 512; // 84992
    if (idx < A) {
        int k = idx >> 9, c = idx & 511;
        wihT16[idx] = __float2half(c < GG ? wih[c * FF + k] : 0.0f);
    } else if (idx < 2 * A) {
        int q = idx - A;
        int k = q >> 9, c = q & 511;
        whhT16[q] = __float2half(c < GG ? whh[c * FF + k] : 0.0f);
    } else if (idx < 2 * A + FF * HH) {
        int q = idx - 2 * A;
        int k = q >> 7, h = q & 127;
        projwT[q] = projw[h * FF + k];
    }
}

// ---------------- CSR build ----------------
__global__ void count_indeg(const int* __restrict__ dst, int* __restrict__ off) {
    int e = blockIdx.x * 256 + threadIdx.x;
    if (e < NE) atomicAdd(&off[dst[e]], 1);
}

__global__ void count_bucket(const int* __restrict__ ts, int* __restrict__ bcnt) {
    int i = blockIdx.x * 256 + threadIdx.x;
    if (i < NN) atomicAdd(&bcnt[ts[i]], 1);
}

__global__ __launch_bounds__(1024) void scan_offsets(int* __restrict__ off) {
    __shared__ int s[1024];
    int tid = threadIdx.x;
    const int CH = (NN + 1023) / 1024; // 196
    int begin = tid * CH;
    int end = begin + CH; if (end > NN) end = NN;
    int sum = 0;
    for (int j = begin; j < end; ++j) sum += off[j];
    s[tid] = sum;
    __syncthreads();
    for (int d = 1; d < 1024; d <<= 1) {
        int v = (tid >= d) ? s[tid - d] : 0;
        __syncthreads();
        s[tid] += v;
        __syncthreads();
    }
    int run = (tid == 0) ? 0 : s[tid - 1];
    for (int j = begin; j < end; ++j) {
        int v = off[j];
        off[j] = run;
        run += v;
    }
    if (tid == 1023) off[NN] = s[1023];
}

__global__ void fill_adj(const int* __restrict__ src, const int* __restrict__ dst,
                         const int* __restrict__ off, int* __restrict__ cursor,
                         int* __restrict__ adjsrc) {
    int e = blockIdx.x * 256 + threadIdx.x;
    if (e < NE) {
        int d = dst[e];
        int p = atomicAdd(&cursor[d], 1);
        adjsrc[off[d] + p] = src[e];
    }
}

// degf[t][i] = 1 + #{in-edges (j->i) : ts[j] <= t}; one histogram pass per node
__global__ __launch_bounds__(256) void degf_hist(const int* __restrict__ off, const int* __restrict__ adjsrc,
                                                 const int* __restrict__ ts, float* __restrict__ degf) {
    __shared__ unsigned short sh[TT * 256];
    int tid = threadIdx.x;
    int i = blockIdx.x * 256 + tid;
    for (int t = 0; t < TT; ++t) sh[t * 256 + tid] = 0;
    if (i >= NN) return;
    int e0 = off[i], e1 = off[i + 1];
    for (int e = e0; e < e1; ++e) {
        int tj = ts[adjsrc[e]];
        sh[tj * 256 + tid]++;
    }
    int cum = 1;
    for (int t = 0; t < TT; ++t) {
        cum += sh[t * 256 + tid];
        degf[(size_t)t * NN + i] = (float)cum;
    }
}

// ---------------- bucket / tile tables (32-row tiles) ----------------
__global__ void make_tiles(const int* __restrict__ bcnt, int* __restrict__ pstart,
                           int* __restrict__ tile_t, int* __restrict__ tile_r0,
                           int* __restrict__ meta) {
    __shared__ int s_nt[64];
    int t = threadIdx.x; // 64 threads
    int nt = (t < TT) ? (bcnt[t] + 31) / 32 : 0;
    s_nt[t] = nt;
    __syncthreads();
    for (int d = 1; d < 64; d <<= 1) {
        int v = (t >= d) ? s_nt[t - d] : 0;
        __syncthreads();
        s_nt[t] += v;
        __syncthreads();
    }
    int ntbase = s_nt[t] - nt;
    int pbase = ntbase * 32;
    if (t < TT) {
        pstart[t] = pbase;
        for (int u = 0; u < nt; ++u) {
            tile_t[ntbase + u] = t;
            tile_r0[ntbase + u] = pbase + u * 32;
        }
    }
    if (t == 63) {
        meta[0] = s_nt[63];
        meta[1] = s_nt[63] * 32;
        pstart[TT] = s_nt[63] * 32;
    }
}

__global__ void perm_fill(const int* __restrict__ ts, const int* __restrict__ pstart,
                          int* __restrict__ bcur, int* __restrict__ perm) {
    int i = blockIdx.x * 256 + threadIdx.x;
    if (i < NN) {
        int t = ts[i];
        int p = atomicAdd(&bcur[t], 1);
        perm[pstart[t] + p] = i;
    }
}

// ---------------- GRU chain: 1 row per block, k split in halves, fp16 weight stream ----------------
__global__ __launch_bounds__(1024) void gru_evolve(
        const float* __restrict__ initial_w,
        const __half* __restrict__ wihT16, const __half* __restrict__ whhT16,
        const float* __restrict__ bih, const float* __restrict__ bhh,
        float* __restrict__ W_all) {
    __shared__ __align__(16) float s_w[168];
    __shared__ float s_pa[2][512];
    __shared__ float s_pb[2][512];
    int tid = threadIdx.x;
    int row = blockIdx.x;                 // 0..165
    int kh = tid >> 9;                    // 0/1 : k-half
    int cp = tid & 511;                   // col-pair index
    bool active = cp < 249;               // 249*2 = 498 gate cols
    int c = cp << 1;

    if (tid < FF) s_w[tid] = initial_w[(size_t)row * FF + tid];
    __syncthreads();

    float bia0 = 0.f, bia1 = 0.f, bib0 = 0.f, bib1 = 0.f;
    if (active && kh == 0) {
        bia0 = bih[c]; bia1 = bih[c + 1];
        bib0 = bhh[c]; bib1 = bhh[c + 1];
    }

    const int kstart = kh * 84;
    const int kcount = 84 - (kh << 1);    // 84 or 82
    const int ngrp = kcount >> 2;         // 21 or 20
    const __half2* __restrict__ pA = (const __half2*)wihT16 + cp;  // idx k*256
    const __half2* __restrict__ pB = (const __half2*)whhT16 + cp;

    for (int t = 0; t < TT; ++t) {
        if (active) {
            float a0 = bia0, a1 = bia1, b0 = bib0, b1 = bib1;
            #pragma unroll 4
            for (int u = 0; u < ngrp; ++u) {
                int k = kstart + (u << 2);
                float4 wv = *(const float4*)&s_w[k];
                float2 fa0 = __half22float2(pA[(size_t)(k + 0) << 8]);
                float2 fb0 = __half22float2(pB[(size_t)(k + 0) << 8]);
                float2 fa1 = __half22float2(pA[(size_t)(k + 1) << 8]);
                float2 fb1 = __half22float2(pB[(size_t)(k + 1) << 8]);
                float2 fa2 = __half22float2(pA[(size_t)(k + 2) << 8]);
                float2 fb2 = __half22float2(pB[(size_t)(k + 2) << 8]);
                float2 fa3 = __half22float2(pA[(size_t)(k + 3) << 8]);
                float2 fb3 = __half22float2(pB[(size_t)(k + 3) << 8]);
                a0 += wv.x * fa0.x; a1 += wv.x * fa0.y; b0 += wv.x * fb0.x; b1 += wv.x * fb0.y;
                a0 += wv.y * fa1.x; a1 += wv.y * fa1.y; b0 += wv.y * fb1.x; b1 += wv.y * fb1.y;
                a0 += wv.z * fa2.x; a1 += wv.z * fa2.y; b0 += wv.z * fb2.x; b1 += wv.z * fb2.y;
                a0 += wv.w * fa3.x; a1 += wv.w * fa3.y; b0 += wv.w * fb3.x; b1 += wv.w * fb3.y;
            }
            for (int k = kstart + (ngrp << 2); k < kstart + kcount; ++k) {
                float wv = s_w[k];
                float2 fa = __half22float2(pA[(size_t)k << 8]);
                float2 fb = __half22float2(pB[(size_t)k << 8]);
                a0 += wv * fa.x; a1 += wv * fa.y; b0 += wv * fb.x; b1 += wv * fb.y;
            }
            *(float2*)&s_pa[kh][c] = make_float2(a0, a1);
            *(float2*)&s_pb[kh][c] = make_float2(b0, b1);
        }
        __syncthreads();   // partials ready
        if (tid < FF) {
            int gc = tid;
            float i_r = s_pa[0][gc] + s_pa[1][gc];
            float h_r = s_pb[0][gc] + s_pb[1][gc];
            float i_z = s_pa[0][FF + gc] + s_pa[1][FF + gc];
            float h_z = s_pb[0][FF + gc] + s_pb[1][FF + gc];
            float i_n = s_pa[0][2 * FF + gc] + s_pa[1][2 * FF + gc];
            float h_n = s_pb[0][2 * FF + gc] + s_pb[1][2 * FF + gc];
            float rg = 1.0f / (1.0f + expf(-(i_r + h_r)));
            float zg = 1.0f / (1.0f + expf(-(i_z + h_z)));
            float ng = tanhf(i_n + rg * h_n);
            float wnew = (1.0f - zg) * ng + zg * s_w[gc];
            s_w[gc] = wnew;
            W_all[((size_t)t * FF + row) * FF + gc] = wnew;
        }
        __syncthreads();   // new W ready
    }
}

// ---------------- M_t[r][h] = sum_c W_t[r][c] * projwT[c][h] ----------------
__global__ __launch_bounds__(1024) void m_build(const float* __restrict__ W_all,
                                                const float* __restrict__ projwT,
                                                float* __restrict__ M_all) {
    __shared__ __align__(16) float sw[8][168];
    int blk = blockIdx.x;
    int t = blk / 21, rb = blk - t * 21;
    int tid = threadIdx.x;
    int r0 = rb * 8;
    for (int idx = tid; idx < 8 * FF; idx += 1024) {
        int rr = idx / FF, k = idx - rr * FF;
        int r = r0 + rr;
        sw[rr][k] = (r < FF) ? W_all[((size_t)t * FF + r) * FF + k] : 0.0f;
    }
    __syncthreads();
    int rr = tid >> 7, h = tid & 127;
    int r = r0 + rr;
    if (r >= FF) return;
    float acc = 0.0f;
    const float* __restrict__ pw = projwT + h;
    #pragma unroll 4
    for (int c4 = 0; c4 < 164; c4 += 4) {
        float4 w = *(const float4*)&sw[rr][c4];
        acc += w.x * pw[(size_t)(c4 + 0) << 7];
        acc += w.y * pw[(size_t)(c4 + 1) << 7];
        acc += w.z * pw[(size_t)(c4 + 2) << 7];
        acc += w.w * pw[(size_t)(c4 + 3) << 7];
    }
    acc += sw[rr][164] * pw[(size_t)164 << 7];
    acc += sw[rr][165] * pw[(size_t)165 << 7];
    M_all[((size_t)t * FF + r) * HH + h] = acc;
}

// ---------------- y build: y_i = x_i/deg_i + sum norm_ij x_j ----------------
__global__ __launch_bounds__(256) void ybuild(const int* __restrict__ perm, const int* __restrict__ ts,
                                              const float* __restrict__ x,
                                              const int* __restrict__ off, const int* __restrict__ adjsrc,
                                              const float* __restrict__ degf, float* __restrict__ Yb) {
    int r = blockIdx.x * 4 + (threadIdx.x >> 6);
    int lane = threadIdx.x & 63;
    int i = perm[r];
    if (i < 0) return;
    int t = ts[i];
    const float* degt = degf + (size_t)t * NN;
    float degi = degt[i];
    float inv_degi = 1.0f / degi;
    float dinv_i = rsqrtf(degi);
    int f1 = lane + 64, f2 = lane + 128;
    const float* xi = x + (size_t)i * FF;
    float a0 = xi[lane] * inv_degi;
    float a1 = xi[f1] * inv_degi;
    float a2 = (f2 < FF) ? xi[f2] * inv_degi : 0.0f;
    int e0 = off[i], e1 = off[i + 1];
    for (int e = e0; e < e1; ++e) {
        int j = adjsrc[e];
        if (ts[j] <= t) {
            float nrm = rsqrtf(degt[j]) * dinv_i;
            const float* xj = x + (size_t)j * FF;
            a0 += nrm * xj[lane];
            a1 += nrm * xj[f1];
            if (f2 < FF) a2 += nrm * xj[f2];
        }
    }
    float* yr = Yb + (size_t)r * FF;
    yr[lane] = a0;
    yr[f1] = a1;
    if (f2 < FF) yr[f2] = a2;
}

// ---------------- fused: P = relu(Y@M_t + proj_b); logits = P@cls^T + cls_b ----------------
__global__ __launch_bounds__(256) void gemm_fused(const int* __restrict__ meta,
                                                  const int* __restrict__ tile_t, const int* __restrict__ tile_r0,
                                                  const int* __restrict__ perm,
                                                  const float* __restrict__ Yb, const float* __restrict__ M_all,
                                                  const float* __restrict__ proj_b,
                                                  const float* __restrict__ cls_w, const float* __restrict__ cls_b,
                                                  float* __restrict__ out) {
    __shared__ float sm[32 * 167];
    int w = blockIdx.x;
    if (w >= meta[0]) return;
    int t = tile_t[w], r0 = tile_r0[w];
    int tid = threadIdx.x;

    for (int idx = tid; idx < 32 * FF; idx += 256) {
        int row = idx / FF, col = idx - row * FF;
        sm[row * 167 + col] = Yb[(size_t)(r0 + row) * FF + col];
    }
    __syncthreads();

    int rg = tid >> 5;
    int cl = tid & 31;
    const float* M = M_all + (size_t)t * (FF * HH);

    float acc[4][4];
    #pragma unroll
    for (int i = 0; i < 4; ++i)
        #pragma unroll
        for (int jj = 0; jj < 4; ++jj) acc[i][jj] = proj_b[cl + 32 * jj];

    #pragma unroll 2
    for (int k = 0; k < FF; ++k) {
        float y0 = sm[(rg * 4 + 0) * 167 + k];
        float y1 = sm[(rg * 4 + 1) * 167 + k];
        float y2 = sm[(rg * 4 + 2) * 167 + k];
        float y3 = sm[(rg * 4 + 3) * 167 + k];
        const float* mk = M + (size_t)k * HH;
        float m0 = mk[cl];
        float m1 = mk[cl + 32];
        float m2 = mk[cl + 64];
        float m3 = mk[cl + 96];
        acc[0][0] += y0 * m0; acc[0][1] += y0 * m1; acc[0][2] += y0 * m2; acc[0][3] += y0 * m3;
        acc[1][0] += y1 * m0; acc[1][1] += y1 * m1; acc[1][2] += y1 * m2; acc[1][3] += y1 * m3;
        acc[2][0] += y2 * m0; acc[2][1] += y2 * m1; acc[2][2] += y2 * m2; acc[2][3] += y2 * m3;
        acc[3][0] += y3 * m0; acc[3][1] += y3 * m1; acc[3][2] += y3 * m2; acc[3][3] += y3 * m3;
    }
    __syncthreads();

    #pragma unroll
    for (int i = 0; i < 4; ++i)
        #pragma unroll
        for (int jj = 0; jj < 4; ++jj)
            sm[(rg * 4 + i) * 130 + cl + 32 * jj] = fmaxf(acc[i][jj], 0.0f);
    __syncthreads();

    if (tid < 64) {
        int row = tid >> 1, cc = tid & 1;
        const float* pr = sm + row * 130;
        const float* cw = cls_w + cc * HH;
        float s = cls_b[cc];
        #pragma unroll 4
        for (int h = 0; h < HH; ++h) s += pr[h] * cw[h];
        int node = perm[r0 + row];
        if (node >= 0) out[(size_t)node * CC + cc] = s;
    }
}

// ---------------- host ----------------
extern "C" void kernel_launch(void* const* d_in, const int* in_sizes, int n_in,
                              void* d_out, int out_size, void* d_ws, size_t ws_size,
                              hipStream_t stream) {
    const float* x = (const float*)d_in[0];
    const int* ei = (const int*)d_in[1];
    const int* srcp = ei;
    const int* dstp = ei + NE;
    const int* ts = (const int*)d_in[2];
    const float* initial_w = (const float*)d_in[3];
    const float* wih = (const float*)d_in[4];
    const float* whh = (const float*)d_in[5];
    const float* bih = (const float*)d_in[6];
    const float* bhh = (const float*)d_in[7];
    const float* projw = (const float*)d_in[8];
    const float* projb = (const float*)d_in[9];
    const float* clsw = (const float*)d_in[10];
    const float* clsb = (const float*)d_in[11];
    float* out = (float*)d_out;

    char* base = (char*)d_ws;
    size_t o = 0;
    auto alloc = [&](size_t bytes) { size_t r = o; o = (o + bytes + 255) & ~(size_t)255; return r; };

    float*  W_all  = (float*) (base + alloc((size_t)TT * FF * FF * 4));
    float*  M_all  = (float*) (base + alloc((size_t)TT * FF * HH * 4));
    __half* wihT16 = (__half*)(base + alloc((size_t)FF * 512 * 2));
    __half* whhT16 = (__half*)(base + alloc((size_t)FF * 512 * 2));
    float*  projwT = (float*) (base + alloc((size_t)FF * HH * 4));
    int*    off    = (int*)   (base + alloc((size_t)(NN + 1) * 4));
    int*    cursor = (int*)   (base + alloc((size_t)NN * 4));
    int*    adjsrc = (int*)   (base + alloc((size_t)NE * 4));
    float*  degf   = (float*) (base + alloc((size_t)TT * NN * 4));
    int*    bcnt   = (int*)   (base + alloc((size_t)TT * 4));
    int*    bcur   = (int*)   (base + alloc((size_t)TT * 4));
    int*    pstart = (int*)   (base + alloc((size_t)(TT + 1) * 4));
    int*    meta   = (int*)   (base + alloc(2 * 4));
    int*    tile_t = (int*)   (base + alloc((size_t)MAXTILES * 4));
    int*    tile_r0= (int*)   (base + alloc((size_t)MAXTILES * 4));
    int*    perm   = (int*)   (base + alloc((size_t)PADN * 4));
    float*  Yb     = (float*) (base + alloc((size_t)PADN * FF * 4));

    hipMemsetAsync(off, 0, (size_t)(NN + 1) * 4, stream);
    hipMemsetAsync(cursor, 0, (size_t)NN * 4, stream);
    hipMemsetAsync(bcnt, 0, (size_t)TT * 4, stream);
    hipMemsetAsync(bcur, 0, (size_t)TT * 4, stream);
    hipMemsetAsync(perm, 0xFF, (size_t)PADN * 4, stream);

    prep_transpose<<<747, 256, 0, stream>>>(wih, whh, projw, wihT16, whhT16, projwT);
    count_indeg<<<(NE + 255) / 256, 256, 0, stream>>>(dstp, off);
    count_bucket<<<(NN + 255) / 256, 256, 0, stream>>>(ts, bcnt);
    scan_offsets<<<1, 1024, 0, stream>>>(off);
    fill_adj<<<(NE + 255) / 256, 256, 0, stream>>>(srcp, dstp, off, cursor, adjsrc);
    degf_hist<<<(NN + 255) / 256, 256, 0, stream>>>(off, adjsrc, ts, degf);
    make_tiles<<<1, 64, 0, stream>>>(bcnt, pstart, tile_t, tile_r0, meta);
    perm_fill<<<(NN + 255) / 256, 256, 0, stream>>>(ts, pstart, bcur, perm);

    gru_evolve<<<FF, 1024, 0, stream>>>(initial_w, wihT16, whhT16, bih, bhh, W_all);
    m_build<<<TT * 21, 1024, 0, stream>>>(W_all, projwT, M_all);

    ybuild<<<PADN / 4, 256, 0, stream>>>(perm, ts, x, off, adjsrc, degf, Yb);

    gemm_fused<<<MAXTILES, 256, 0, stream>>>(meta, tile_t, tile_r0, perm, Yb, M_all,
                                             projb, clsw, clsb, out);
}

// Round 4
// 1254.209 us; speedup vs baseline: 2.2644x; 1.3265x over previous
//
#include <hip/hip_runtime.h>
#include <hip/hip_fp16.h>
#include <math.h>

#define NN 200000
#define NE 500000
#define FF 166
#define HH 128
#define CC 2
#define TT 49
#define GG 498            // 3*FF
#define PADN 203136
#define MAXTILES 6400
#define KP 84             // k-pairs (166 -> 84 half2, padded)
#define SCB 512           // scan elements per block
#define SNB 391           // ceil(NN/512)

typedef _Float16 half2v __attribute__((ext_vector_type(2)));

static __device__ __forceinline__ float fdot2f(half2v a, half2v b, float c) {
#if __has_builtin(__builtin_amdgcn_fdot2)
    return __builtin_amdgcn_fdot2(a, b, c, false);
#else
    return c + (float)a.x * (float)b.x + (float)a.y * (float)b.y;
#endif
}

// ---------------- prep: pack GRU weights as [m][kp][512] half2 (k-pairs), fp32 projT ----------------
__global__ void prep_pack(const float* __restrict__ wih, const float* __restrict__ whh,
                          const float* __restrict__ projw,
                          _Float16* __restrict__ wkp, float* __restrict__ projwT) {
    int idx = blockIdx.x * 256 + threadIdx.x;
    const int A = 2 * KP * 512; // 86016 half2 slots
    if (idx < A) {
        int m = idx / (KP * 512);
        int r = idx - m * (KP * 512);
        int kp = r >> 9, c = r & 511;
        const float* Wm = m ? whh : wih;
        float x0 = 0.0f, x1 = 0.0f;
        if (c < GG) {
            int k0 = 2 * kp, k1 = 2 * kp + 1;
            if (k0 < FF) x0 = Wm[c * FF + k0];
            if (k1 < FF) x1 = Wm[c * FF + k1];
        }
        wkp[2 * idx]     = (_Float16)x0;
        wkp[2 * idx + 1] = (_Float16)x1;
    } else if (idx < A + FF * HH) {
        int q = idx - A;
        int k = q >> 7, h = q & 127;
        projwT[q] = projw[h * FF + k];
    }
}

// ---------------- CSR build ----------------
__global__ void count_indeg(const int* __restrict__ dst, int* __restrict__ off) {
    int e = blockIdx.x * 256 + threadIdx.x;
    if (e < NE) atomicAdd(&off[dst[e]], 1);
}

__global__ void count_bucket(const int* __restrict__ ts, int* __restrict__ bcnt) {
    int i = blockIdx.x * 256 + threadIdx.x;
    if (i < NN) atomicAdd(&bcnt[ts[i]], 1);
}

// ---- 3-phase multi-block exclusive scan of off[0..NN) ----
__global__ __launch_bounds__(256) void scan_p1(const int* __restrict__ off, int* __restrict__ bsum) {
    __shared__ int s[256];
    int b = blockIdx.x, tid = threadIdx.x;
    int i0 = b * SCB + tid * 2;
    int v = 0;
    if (i0 < NN) v += off[i0];
    if (i0 + 1 < NN) v += off[i0 + 1];
    s[tid] = v;
    __syncthreads();
    for (int d = 128; d > 0; d >>= 1) {
        if (tid < d) s[tid] += s[tid + d];
        __syncthreads();
    }
    if (tid == 0) bsum[b] = s[0];
}

__global__ __launch_bounds__(512) void scan_p2(const int* __restrict__ bsum, int* __restrict__ bpre,
                                               int* __restrict__ off) {
    __shared__ int s[512];
    int tid = threadIdx.x;
    int v = (tid < SNB) ? bsum[tid] : 0;
    s[tid] = v;
    __syncthreads();
    for (int d = 1; d < 512; d <<= 1) {
        int u = (tid >= d) ? s[tid - d] : 0;
        __syncthreads();
        s[tid] += u;
        __syncthreads();
    }
    bpre[tid] = s[tid] - v;  // exclusive
    if (tid == 511) off[NN] = s[511];  // total edges
}

__global__ __launch_bounds__(512) void scan_p3(int* __restrict__ off, const int* __restrict__ bpre) {
    __shared__ int s[512];
    int b = blockIdx.x, tid = threadIdx.x;
    int i = b * SCB + tid;
    int v = (i < NN) ? off[i] : 0;
    s[tid] = v;
    __syncthreads();
    for (int d = 1; d < 512; d <<= 1) {
        int u = (tid >= d) ? s[tid - d] : 0;
        __syncthreads();
        s[tid] += u;
        __syncthreads();
    }
    if (i < NN) off[i] = s[tid] - v + bpre[b];
}

__global__ void fill_adj(const int* __restrict__ src, const int* __restrict__ dst,
                         const int* __restrict__ off, int* __restrict__ cursor,
                         int* __restrict__ adjsrc) {
    int e = blockIdx.x * 256 + threadIdx.x;
    if (e < NE) {
        int d = dst[e];
        int p = atomicAdd(&cursor[d], 1);
        adjsrc[off[d] + p] = src[e];
    }
}

// degf[t][i] = 1 + #{in-edges (j->i) : ts[j] <= t}; one histogram pass per node
__global__ __launch_bounds__(256) void degf_hist(const int* __restrict__ off, const int* __restrict__ adjsrc,
                                                 const int* __restrict__ ts, float* __restrict__ degf) {
    __shared__ unsigned short sh[TT * 256];
    int tid = threadIdx.x;
    int i = blockIdx.x * 256 + tid;
    for (int t = 0; t < TT; ++t) sh[t * 256 + tid] = 0;
    if (i >= NN) return;
    int e0 = off[i], e1 = off[i + 1];
    for (int e = e0; e < e1; ++e) {
        int tj = ts[adjsrc[e]];
        sh[tj * 256 + tid]++;
    }
    int cum = 1;
    for (int t = 0; t < TT; ++t) {
        cum += sh[t * 256 + tid];
        degf[(size_t)t * NN + i] = (float)cum;
    }
}

// ---------------- bucket / tile tables (32-row tiles) ----------------
__global__ void make_tiles(const int* __restrict__ bcnt, int* __restrict__ pstart,
                           int* __restrict__ tile_t, int* __restrict__ tile_r0,
                           int* __restrict__ meta) {
    __shared__ int s_nt[64];
    int t = threadIdx.x; // 64 threads
    int nt = (t < TT) ? (bcnt[t] + 31) / 32 : 0;
    s_nt[t] = nt;
    __syncthreads();
    for (int d = 1; d < 64; d <<= 1) {
        int v = (t >= d) ? s_nt[t - d] : 0;
        __syncthreads();
        s_nt[t] += v;
        __syncthreads();
    }
    int ntbase = s_nt[t] - nt;
    int pbase = ntbase * 32;
    if (t < TT) {
        pstart[t] = pbase;
        for (int u = 0; u < nt; ++u) {
            tile_t[ntbase + u] = t;
            tile_r0[ntbase + u] = pbase + u * 32;
        }
    }
    if (t == 63) {
        meta[0] = s_nt[63];
        meta[1] = s_nt[63] * 32;
        pstart[TT] = s_nt[63] * 32;
    }
}

__global__ void perm_fill(const int* __restrict__ ts, const int* __restrict__ pstart,
                          int* __restrict__ bcur, int* __restrict__ perm) {
    int i = blockIdx.x * 256 + threadIdx.x;
    if (i < NN) {
        int t = ts[i];
        int p = atomicAdd(&bcur[t], 1);
        perm[pstart[t] + p] = i;
    }
}

// ---------------- GRU chain: 1 row/block, thread=(matrix m, gate col c), dot2 inner ----------------
__global__ __launch_bounds__(1024) void gru_evolve(
        const float* __restrict__ initial_w,
        const _Float16* __restrict__ wkp,      // [2][KP][512] half2
        const float* __restrict__ bih, const float* __restrict__ bhh,
        float* __restrict__ W_all) {
    __shared__ float s_w[FF];
    __shared__ __align__(8) _Float16 s_wh[2 * KP];   // 168, padded with zeros
    __shared__ float s_pre[2][512];
    int tid = threadIdx.x;
    int row = blockIdx.x;

    if (tid < FF) {
        float v = initial_w[(size_t)row * FF + tid];
        s_w[tid] = v;
        s_wh[tid] = (_Float16)v;
    } else if (tid < 2 * KP) {
        s_wh[tid] = (_Float16)0.0f;
    }

    int m = (tid >= 498) ? 1 : 0;
    int c = tid - m * 498;
    bool act = tid < 996;
    const half2v* __restrict__ pW = (const half2v*)wkp + (size_t)m * KP * 512 + (act ? c : 0);
    const half2v* s_wh2 = (const half2v*)s_wh;

    // gate-combine thread biases (tid < FF)
    float bi_r = 0, bi_z = 0, bi_n = 0, bh_r = 0, bh_z = 0, bh_n = 0;
    if (tid < FF) {
        bi_r = bih[tid]; bi_z = bih[FF + tid]; bi_n = bih[2 * FF + tid];
        bh_r = bhh[tid]; bh_z = bhh[FF + tid]; bh_n = bhh[2 * FF + tid];
    }
    __syncthreads();

    for (int t = 0; t < TT; ++t) {
        if (act) {
            float acc = 0.0f;
            #pragma unroll 4
            for (int kp = 0; kp < KP; ++kp) {
                half2v w2 = s_wh2[kp];
                half2v g2 = pW[(size_t)kp << 9];
                acc = fdot2f(g2, w2, acc);
            }
            s_pre[m][c] = acc;
        }
        __syncthreads();   // pre-activations ready
        if (tid < FF) {
            float i_r = s_pre[0][tid]          + bi_r;
            float h_r = s_pre[1][tid]          + bh_r;
            float i_z = s_pre[0][FF + tid]     + bi_z;
            float h_z = s_pre[1][FF + tid]     + bh_z;
            float i_n = s_pre[0][2 * FF + tid] + bi_n;
            float h_n = s_pre[1][2 * FF + tid] + bh_n;
            float rg = 1.0f / (1.0f + expf(-(i_r + h_r)));
            float zg = 1.0f / (1.0f + expf(-(i_z + h_z)));
            float ng = tanhf(i_n + rg * h_n);
            float wnew = (1.0f - zg) * ng + zg * s_w[tid];
            s_w[tid] = wnew;
            s_wh[tid] = (_Float16)wnew;
            W_all[((size_t)t * FF + row) * FF + tid] = wnew;
        }
        __syncthreads();   // new W ready for next matvec; s_pre safe to overwrite
    }
}

// ---------------- M_t[r][h] = sum_c W_t[r][c] * projwT[c][h] ----------------
__global__ __launch_bounds__(1024) void m_build(const float* __restrict__ W_all,
                                                const float* __restrict__ projwT,
                                                float* __restrict__ M_all) {
    __shared__ __align__(16) float sw[8][168];
    int blk = blockIdx.x;
    int t = blk / 21, rb = blk - t * 21;
    int tid = threadIdx.x;
    int r0 = rb * 8;
    for (int idx = tid; idx < 8 * FF; idx += 1024) {
        int rr = idx / FF, k = idx - rr * FF;
        int r = r0 + rr;
        sw[rr][k] = (r < FF) ? W_all[((size_t)t * FF + r) * FF + k] : 0.0f;
    }
    __syncthreads();
    int rr = tid >> 7, h = tid & 127;
    int r = r0 + rr;
    if (r >= FF) return;
    float acc = 0.0f;
    const float* __restrict__ pw = projwT + h;
    #pragma unroll 4
    for (int c4 = 0; c4 < 164; c4 += 4) {
        float4 w = *(const float4*)&sw[rr][c4];
        acc += w.x * pw[(size_t)(c4 + 0) << 7];
        acc += w.y * pw[(size_t)(c4 + 1) << 7];
        acc += w.z * pw[(size_t)(c4 + 2) << 7];
        acc += w.w * pw[(size_t)(c4 + 3) << 7];
    }
    acc += sw[rr][164] * pw[(size_t)164 << 7];
    acc += sw[rr][165] * pw[(size_t)165 << 7];
    M_all[((size_t)t * FF + r) * HH + h] = acc;
}

// ---------------- y build: y_i = x_i/deg_i + sum norm_ij x_j ----------------
__global__ __launch_bounds__(256) void ybuild(const int* __restrict__ perm, const int* __restrict__ ts,
                                              const float* __restrict__ x,
                                              const int* __restrict__ off, const int* __restrict__ adjsrc,
                                              const float* __restrict__ degf, float* __restrict__ Yb) {
    int r = blockIdx.x * 4 + (threadIdx.x >> 6);
    int lane = threadIdx.x & 63;
    int i = perm[r];
    if (i < 0) return;
    int t = ts[i];
    const float* degt = degf + (size_t)t * NN;
    float degi = degt[i];
    float inv_degi = 1.0f / degi;
    float dinv_i = rsqrtf(degi);
    int f1 = lane + 64, f2 = lane + 128;
    const float* xi = x + (size_t)i * FF;
    float a0 = xi[lane] * inv_degi;
    float a1 = xi[f1] * inv_degi;
    float a2 = (f2 < FF) ? xi[f2] * inv_degi : 0.0f;
    int e0 = off[i], e1 = off[i + 1];
    for (int e = e0; e < e1; ++e) {
        int j = adjsrc[e];
        if (ts[j] <= t) {
            float nrm = rsqrtf(degt[j]) * dinv_i;
            const float* xj = x + (size_t)j * FF;
            a0 += nrm * xj[lane];
            a1 += nrm * xj[f1];
            if (f2 < FF) a2 += nrm * xj[f2];
        }
    }
    float* yr = Yb + (size_t)r * FF;
    yr[lane] = a0;
    yr[f1] = a1;
    if (f2 < FF) yr[f2] = a2;
}

// ---------------- fused: P = relu(Y@M_t + proj_b); logits = P@cls^T + cls_b ----------------
__global__ __launch_bounds__(256) void gemm_fused(const int* __restrict__ meta,
                                                  const int* __restrict__ tile_t, const int* __restrict__ tile_r0,
                                                  const int* __restrict__ perm,
                                                  const float* __restrict__ Yb, const float* __restrict__ M_all,
                                                  const float* __restrict__ proj_b,
                                                  const float* __restrict__ cls_w, const float* __restrict__ cls_b,
                                                  float* __restrict__ out) {
    __shared__ float sm[32 * 167];
    int w = blockIdx.x;
    if (w >= meta[0]) return;
    int t = tile_t[w], r0 = tile_r0[w];
    int tid = threadIdx.x;

    for (int idx = tid; idx < 32 * FF; idx += 256) {
        int row = idx / FF, col = idx - row * FF;
        sm[row * 167 + col] = Yb[(size_t)(r0 + row) * FF + col];
    }
    __syncthreads();

    int rg = tid >> 5;
    int cl = tid & 31;
    const float* M = M_all + (size_t)t * (FF * HH);

    float acc[4][4];
    #pragma unroll
    for (int i = 0; i < 4; ++i)
        #pragma unroll
        for (int jj = 0; jj < 4; ++jj) acc[i][jj] = proj_b[cl + 32 * jj];

    #pragma unroll 2
    for (int k = 0; k < FF; ++k) {
        float y0 = sm[(rg * 4 + 0) * 167 + k];
        float y1 = sm[(rg * 4 + 1) * 167 + k];
        float y2 = sm[(rg * 4 + 2) * 167 + k];
        float y3 = sm[(rg * 4 + 3) * 167 + k];
        const float* mk = M + (size_t)k * HH;
        float m0 = mk[cl];
        float m1 = mk[cl + 32];
        float m2 = mk[cl + 64];
        float m3 = mk[cl + 96];
        acc[0][0] += y0 * m0; acc[0][1] += y0 * m1; acc[0][2] += y0 * m2; acc[0][3] += y0 * m3;
        acc[1][0] += y1 * m0; acc[1][1] += y1 * m1; acc[1][2] += y1 * m2; acc[1][3] += y1 * m3;
        acc[2][0] += y2 * m0; acc[2][1] += y2 * m1; acc[2][2] += y2 * m2; acc[2][3] += y2 * m3;
        acc[3][0] += y3 * m0; acc[3][1] += y3 * m1; acc[3][2] += y3 * m2; acc[3][3] += y3 * m3;
    }
    __syncthreads();

    #pragma unroll
    for (int i = 0; i < 4; ++i)
        #pragma unroll
        for (int jj = 0; jj < 4; ++jj)
            sm[(rg * 4 + i) * 130 + cl + 32 * jj] = fmaxf(acc[i][jj], 0.0f);
    __syncthreads();

    if (tid < 64) {
        int row = tid >> 1, cc = tid & 1;
        const float* pr = sm + row * 130;
        const float* cw = cls_w + cc * HH;
        float s = cls_b[cc];
        #pragma unroll 4
        for (int h = 0; h < HH; ++h) s += pr[h] * cw[h];
        int node = perm[r0 + row];
        if (node >= 0) out[(size_t)node * CC + cc] = s;
    }
}

// ---------------- host ----------------
extern "C" void kernel_launch(void* const* d_in, const int* in_sizes, int n_in,
                              void* d_out, int out_size, void* d_ws, size_t ws_size,
                              hipStream_t stream) {
    const float* x = (const float*)d_in[0];
    const int* ei = (const int*)d_in[1];
    const int* srcp = ei;
    const int* dstp = ei + NE;
    const int* ts = (const int*)d_in[2];
    const float* initial_w = (const float*)d_in[3];
    const float* wih = (const float*)d_in[4];
    const float* whh = (const float*)d_in[5];
    const float* bih = (const float*)d_in[6];
    const float* bhh = (const float*)d_in[7];
    const float* projw = (const float*)d_in[8];
    const float* projb = (const float*)d_in[9];
    const float* clsw = (const float*)d_in[10];
    const float* clsb = (const float*)d_in[11];
    float* out = (float*)d_out;

    char* base = (char*)d_ws;
    size_t o = 0;
    auto alloc = [&](size_t bytes) { size_t r = o; o = (o + bytes + 255) & ~(size_t)255; return r; };

    float*    W_all  = (float*)   (base + alloc((size_t)TT * FF * FF * 4));
    float*    M_all  = (float*)   (base + alloc((size_t)TT * FF * HH * 4));
    _Float16* wkp    = (_Float16*)(base + alloc((size_t)2 * KP * 512 * 2 * 2));
    float*    projwT = (float*)   (base + alloc((size_t)FF * HH * 4));
    int*      off    = (int*)     (base + alloc((size_t)(NN + 1) * 4));
    int*      cursor = (int*)     (base + alloc((size_t)NN * 4));
    int*      adjsrc = (int*)     (base + alloc((size_t)NE * 4));
    float*    degf   = (float*)   (base + alloc((size_t)TT * NN * 4));
    int*      bcnt   = (int*)     (base + alloc((size_t)TT * 4));
    int*      bcur   = (int*)     (base + alloc((size_t)TT * 4));
    int*      pstart = (int*)     (base + alloc((size_t)(TT + 1) * 4));
    int*      meta   = (int*)     (base + alloc(2 * 4));
    int*      tile_t = (int*)     (base + alloc((size_t)MAXTILES * 4));
    int*      tile_r0= (int*)     (base + alloc((size_t)MAXTILES * 4));
    int*      perm   = (int*)     (base + alloc((size_t)PADN * 4));
    int*      bsum   = (int*)     (base + alloc((size_t)512 * 4));
    int*      bpre   = (int*)     (base + alloc((size_t)520 * 4));
    float*    Yb     = (float*)   (base + alloc((size_t)PADN * FF * 4));

    hipMemsetAsync(off, 0, (size_t)(NN + 1) * 4, stream);
    hipMemsetAsync(cursor, 0, (size_t)NN * 4, stream);
    hipMemsetAsync(bcnt, 0, (size_t)TT * 4, stream);
    hipMemsetAsync(bcur, 0, (size_t)TT * 4, stream);
    hipMemsetAsync(perm, 0xFF, (size_t)PADN * 4, stream);

    prep_pack<<<420, 256, 0, stream>>>(wih, whh, projw, wkp, projwT);
    count_indeg<<<(NE + 255) / 256, 256, 0, stream>>>(dstp, off);
    count_bucket<<<(NN + 255) / 256, 256, 0, stream>>>(ts, bcnt);
    scan_p1<<<SNB, 256, 0, stream>>>(off, bsum);
    scan_p2<<<1, 512, 0, stream>>>(bsum, bpre, off);
    scan_p3<<<SNB, 512, 0, stream>>>(off, bpre);
    fill_adj<<<(NE + 255) / 256, 256, 0, stream>>>(srcp, dstp, off, cursor, adjsrc);
    degf_hist<<<(NN + 255) / 256, 256, 0, stream>>>(off, adjsrc, ts, degf);
    make_tiles<<<1, 64, 0, stream>>>(bcnt, pstart, tile_t, tile_r0, meta);
    perm_fill<<<(NN + 255) / 256, 256, 0, stream>>>(ts, pstart, bcur, perm);

    gru_evolve<<<FF, 1024, 0, stream>>>(initial_w, wkp, bih, bhh, W_all);
    m_build<<<TT * 21, 1024, 0, stream>>>(W_all, projwT, M_all);

    ybuild<<<PADN / 4, 256, 0, stream>>>(perm, ts, x, off, adjsrc, degf, Yb);

    gemm_fused<<<MAXTILES, 256, 0, stream>>>(meta, tile_t, tile_r0, perm, Yb, M_all,
                                             projb, clsw, clsb, out);
}

// Round 5
// 662.125 us; speedup vs baseline: 4.2892x; 1.8942x over previous
//
#include <hip/hip_runtime.h>
#include <hip/hip_fp16.h>
#include <math.h>

#define NN 200000
#define NE 500000
#define FF 166
#define HH 128
#define CC 2
#define TT 49
#define GG 498            // 3*FF
#define PADN 203136
#define MAXTILES 6400
#define KP 84             // k-pairs (166 -> 84 half2, padded)
#define SCB 512           // scan elements per block
#define SNB 391           // ceil(NN/512)
#define HB 782            // ceil(NN/256) histogram blocks

typedef _Float16 half2v __attribute__((ext_vector_type(2)));

static __device__ __forceinline__ float fdot2f(half2v a, half2v b, float c) {
#if __has_builtin(__builtin_amdgcn_fdot2)
    return __builtin_amdgcn_fdot2(a, b, c, false);
#else
    return c + (float)a.x * (float)b.x + (float)a.y * (float)b.y;
#endif
}

// ---------------- prep: pack GRU weights as [m][kp][512] half2 (k-pairs), fp32 projT ----------------
__global__ void prep_pack(const float* __restrict__ wih, const float* __restrict__ whh,
                          const float* __restrict__ projw,
                          _Float16* __restrict__ wkp, float* __restrict__ projwT) {
    int idx = blockIdx.x * 256 + threadIdx.x;
    const int A = 2 * KP * 512; // 86016 half2 slots
    if (idx < A) {
        int m = idx / (KP * 512);
        int r = idx - m * (KP * 512);
        int kp = r >> 9, c = r & 511;
        const float* Wm = m ? whh : wih;
        float x0 = 0.0f, x1 = 0.0f;
        if (c < GG) {
            int k0 = 2 * kp, k1 = 2 * kp + 1;
            if (k0 < FF) x0 = Wm[c * FF + k0];
            if (k1 < FF) x1 = Wm[c * FF + k1];
        }
        wkp[2 * idx]     = (_Float16)x0;
        wkp[2 * idx + 1] = (_Float16)x1;
    } else if (idx < A + FF * HH) {
        int q = idx - A;
        int k = q >> 7, h = q & 127;
        projwT[q] = projw[h * FF + k];
    }
}

// ---------------- CSR build ----------------
__global__ void count_indeg(const int* __restrict__ dst, int* __restrict__ off) {
    int e = blockIdx.x * 256 + threadIdx.x;
    if (e < NE) atomicAdd(&off[dst[e]], 1);
}

// ---- 3-phase multi-block exclusive scan of off[0..NN) ----
__global__ __launch_bounds__(256) void scan_p1(const int* __restrict__ off, int* __restrict__ bsum) {
    __shared__ int s[256];
    int b = blockIdx.x, tid = threadIdx.x;
    int i0 = b * SCB + tid * 2;
    int v = 0;
    if (i0 < NN) v += off[i0];
    if (i0 + 1 < NN) v += off[i0 + 1];
    s[tid] = v;
    __syncthreads();
    for (int d = 128; d > 0; d >>= 1) {
        if (tid < d) s[tid] += s[tid + d];
        __syncthreads();
    }
    if (tid == 0) bsum[b] = s[0];
}

__global__ __launch_bounds__(512) void scan_p2(const int* __restrict__ bsum, int* __restrict__ bpre,
                                               int* __restrict__ off) {
    __shared__ int s[512];
    int tid = threadIdx.x;
    int v = (tid < SNB) ? bsum[tid] : 0;
    s[tid] = v;
    __syncthreads();
    for (int d = 1; d < 512; d <<= 1) {
        int u = (tid >= d) ? s[tid - d] : 0;
        __syncthreads();
        s[tid] += u;
        __syncthreads();
    }
    bpre[tid] = s[tid] - v;  // exclusive
    if (tid == 511) off[NN] = s[511];  // total edges
}

__global__ __launch_bounds__(512) void scan_p3(int* __restrict__ off, const int* __restrict__ bpre) {
    __shared__ int s[512];
    int b = blockIdx.x, tid = threadIdx.x;
    int i = b * SCB + tid;
    int v = (i < NN) ? off[i] : 0;
    s[tid] = v;
    __syncthreads();
    for (int d = 1; d < 512; d <<= 1) {
        int u = (tid >= d) ? s[tid - d] : 0;
        __syncthreads();
        s[tid] += u;
        __syncthreads();
    }
    if (i < NN) off[i] = s[tid] - v + bpre[b];
}

__global__ void fill_adj(const int* __restrict__ src, const int* __restrict__ dst,
                         const int* __restrict__ off, int* __restrict__ cursor,
                         int* __restrict__ adjsrc) {
    int e = blockIdx.x * 256 + threadIdx.x;
    if (e < NE) {
        int d = dst[e];
        int p = atomicAdd(&cursor[d], 1);
        adjsrc[off[d] + p] = src[e];
    }
}

// degf[t][i] = 1 + #{in-edges (j->i) : ts[j] <= t}; one histogram pass per node
__global__ __launch_bounds__(256) void degf_hist(const int* __restrict__ off, const int* __restrict__ adjsrc,
                                                 const int* __restrict__ ts, float* __restrict__ degf) {
    __shared__ unsigned short sh[TT * 256];
    int tid = threadIdx.x;
    int i = blockIdx.x * 256 + tid;
    for (int t = 0; t < TT; ++t) sh[t * 256 + tid] = 0;
    if (i >= NN) return;
    int e0 = off[i], e1 = off[i + 1];
    for (int e = e0; e < e1; ++e) {
        int tj = ts[adjsrc[e]];
        sh[tj * 256 + tid]++;
    }
    int cum = 1;
    for (int t = 0; t < TT; ++t) {
        cum += sh[t * 256 + tid];
        degf[(size_t)t * NN + i] = (float)cum;
    }
}

// ---------------- counting sort of nodes by time bucket (no global atomics) ----------------
__global__ __launch_bounds__(256) void hist_rank(const int* __restrict__ ts,
                                                 int* __restrict__ cnt, int* __restrict__ rank) {
    __shared__ int h[TT];
    int tid = threadIdx.x, b = blockIdx.x;
    if (tid < TT) h[tid] = 0;
    __syncthreads();
    int i = b * 256 + tid;
    if (i < NN) {
        int t = ts[i];
        rank[i] = atomicAdd(&h[t], 1);   // LDS atomic: cheap
    }
    __syncthreads();
    if (tid < TT) cnt[b * TT + tid] = h[tid];
}

__global__ __launch_bounds__(256) void bucket_scan(const int* __restrict__ cnt,
                                                   int* __restrict__ basecol, int* __restrict__ bcnt) {
    __shared__ int s[256];
    int t = blockIdx.x, tid = threadIdx.x;
    const int CH = (HB + 255) / 256; // 4
    int b0 = tid * CH;
    int loc[CH];
    int sum = 0;
    for (int u = 0; u < CH; ++u) {
        int b = b0 + u;
        int v = (b < HB) ? cnt[b * TT + t] : 0;
        loc[u] = sum;
        sum += v;
    }
    s[tid] = sum;
    __syncthreads();
    for (int d = 1; d < 256; d <<= 1) {
        int u = (tid >= d) ? s[tid - d] : 0;
        __syncthreads();
        s[tid] += u;
        __syncthreads();
    }
    int base = s[tid] - sum;   // exclusive prefix for this thread's chunk
    for (int u = 0; u < CH; ++u) {
        int b = b0 + u;
        if (b < HB) basecol[b * TT + t] = base + loc[u];
    }
    if (tid == 255) bcnt[t] = s[255];
}

__global__ __launch_bounds__(256) void perm_scatter(const int* __restrict__ ts, const int* __restrict__ rank,
                                                    const int* __restrict__ basecol, const int* __restrict__ pstart,
                                                    int* __restrict__ perm) {
    int b = blockIdx.x;
    int i = b * 256 + threadIdx.x;
    if (i < NN) {
        int t = ts[i];
        perm[pstart[t] + basecol[b * TT + t] + rank[i]] = i;
    }
}

// ---------------- bucket / tile tables (32-row tiles) ----------------
__global__ void make_tiles(const int* __restrict__ bcnt, int* __restrict__ pstart,
                           int* __restrict__ tile_t, int* __restrict__ tile_r0,
                           int* __restrict__ meta) {
    __shared__ int s_nt[64];
    int t = threadIdx.x; // 64 threads
    int nt = (t < TT) ? (bcnt[t] + 31) / 32 : 0;
    s_nt[t] = nt;
    __syncthreads();
    for (int d = 1; d < 64; d <<= 1) {
        int v = (t >= d) ? s_nt[t - d] : 0;
        __syncthreads();
        s_nt[t] += v;
        __syncthreads();
    }
    int ntbase = s_nt[t] - nt;
    int pbase = ntbase * 32;
    if (t < TT) {
        pstart[t] = pbase;
        for (int u = 0; u < nt; ++u) {
            tile_t[ntbase + u] = t;
            tile_r0[ntbase + u] = pbase + u * 32;
        }
    }
    if (t == 63) {
        meta[0] = s_nt[63];
        meta[1] = s_nt[63] * 32;
        pstart[TT] = s_nt[63] * 32;
    }
}

// ---------------- GRU chain: 1 row/block, thread=(matrix m, gate col c), dot2 inner ----------------
__global__ __launch_bounds__(1024) void gru_evolve(
        const float* __restrict__ initial_w,
        const _Float16* __restrict__ wkp,      // [2][KP][512] half2
        const float* __restrict__ bih, const float* __restrict__ bhh,
        float* __restrict__ W_all) {
    __shared__ float s_w[FF];
    __shared__ __align__(8) _Float16 s_wh[2 * KP];   // 168, padded with zeros
    __shared__ float s_pre[2][512];
    int tid = threadIdx.x;
    int row = blockIdx.x;

    if (tid < FF) {
        float v = initial_w[(size_t)row * FF + tid];
        s_w[tid] = v;
        s_wh[tid] = (_Float16)v;
    } else if (tid < 2 * KP) {
        s_wh[tid] = (_Float16)0.0f;
    }

    int m = (tid >= 498) ? 1 : 0;
    int c = tid - m * 498;
    bool act = tid < 996;
    const half2v* __restrict__ pW = (const half2v*)wkp + (size_t)m * KP * 512 + (act ? c : 0);
    const half2v* s_wh2 = (const half2v*)s_wh;

    float bi_r = 0, bi_z = 0, bi_n = 0, bh_r = 0, bh_z = 0, bh_n = 0;
    if (tid < FF) {
        bi_r = bih[tid]; bi_z = bih[FF + tid]; bi_n = bih[2 * FF + tid];
        bh_r = bhh[tid]; bh_z = bhh[FF + tid]; bh_n = bhh[2 * FF + tid];
    }
    __syncthreads();

    for (int t = 0; t < TT; ++t) {
        if (act) {
            float acc = 0.0f;
            #pragma unroll 4
            for (int kp = 0; kp < KP; ++kp) {
                half2v w2 = s_wh2[kp];
                half2v g2 = pW[(size_t)kp << 9];
                acc = fdot2f(g2, w2, acc);
            }
            s_pre[m][c] = acc;
        }
        __syncthreads();
        if (tid < FF) {
            float i_r = s_pre[0][tid]          + bi_r;
            float h_r = s_pre[1][tid]          + bh_r;
            float i_z = s_pre[0][FF + tid]     + bi_z;
            float h_z = s_pre[1][FF + tid]     + bh_z;
            float i_n = s_pre[0][2 * FF + tid] + bi_n;
            float h_n = s_pre[1][2 * FF + tid] + bh_n;
            float rg = 1.0f / (1.0f + expf(-(i_r + h_r)));
            float zg = 1.0f / (1.0f + expf(-(i_z + h_z)));
            float ng = tanhf(i_n + rg * h_n);
            float wnew = (1.0f - zg) * ng + zg * s_w[tid];
            s_w[tid] = wnew;
            s_wh[tid] = (_Float16)wnew;
            W_all[((size_t)t * FF + row) * FF + tid] = wnew;
        }
        __syncthreads();
    }
}

// ---------------- M_t[r][h] = sum_c W_t[r][c] * projwT[c][h] ----------------
__global__ __launch_bounds__(1024) void m_build(const float* __restrict__ W_all,
                                                const float* __restrict__ projwT,
                                                float* __restrict__ M_all) {
    __shared__ __align__(16) float sw[8][168];
    int blk = blockIdx.x;
    int t = blk / 21, rb = blk - t * 21;
    int tid = threadIdx.x;
    int r0 = rb * 8;
    for (int idx = tid; idx < 8 * FF; idx += 1024) {
        int rr = idx / FF, k = idx - rr * FF;
        int r = r0 + rr;
        sw[rr][k] = (r < FF) ? W_all[((size_t)t * FF + r) * FF + k] : 0.0f;
    }
    __syncthreads();
    int rr = tid >> 7, h = tid & 127;
    int r = r0 + rr;
    if (r >= FF) return;
    float acc = 0.0f;
    const float* __restrict__ pw = projwT + h;
    #pragma unroll 4
    for (int c4 = 0; c4 < 164; c4 += 4) {
        float4 w = *(const float4*)&sw[rr][c4];
        acc += w.x * pw[(size_t)(c4 + 0) << 7];
        acc += w.y * pw[(size_t)(c4 + 1) << 7];
        acc += w.z * pw[(size_t)(c4 + 2) << 7];
        acc += w.w * pw[(size_t)(c4 + 3) << 7];
    }
    acc += sw[rr][164] * pw[(size_t)164 << 7];
    acc += sw[rr][165] * pw[(size_t)165 << 7];
    M_all[((size_t)t * FF + r) * HH + h] = acc;
}

// ---------------- y build: y_i = x_i/deg_i + sum norm_ij x_j ----------------
__global__ __launch_bounds__(256) void ybuild(const int* __restrict__ perm, const int* __restrict__ ts,
                                              const float* __restrict__ x,
                                              const int* __restrict__ off, const int* __restrict__ adjsrc,
                                              const float* __restrict__ degf, float* __restrict__ Yb) {
    int r = blockIdx.x * 4 + (threadIdx.x >> 6);
    int lane = threadIdx.x & 63;
    int i = perm[r];
    if (i < 0) return;
    int t = ts[i];
    const float* degt = degf + (size_t)t * NN;
    float degi = degt[i];
    float inv_degi = 1.0f / degi;
    float dinv_i = rsqrtf(degi);
    int f1 = lane + 64, f2 = lane + 128;
    const float* xi = x + (size_t)i * FF;
    float a0 = xi[lane] * inv_degi;
    float a1 = xi[f1] * inv_degi;
    float a2 = (f2 < FF) ? xi[f2] * inv_degi : 0.0f;
    int e0 = off[i], e1 = off[i + 1];
    for (int e = e0; e < e1; ++e) {
        int j = adjsrc[e];
        if (ts[j] <= t) {
            float nrm = rsqrtf(degt[j]) * dinv_i;
            const float* xj = x + (size_t)j * FF;
            a0 += nrm * xj[lane];
            a1 += nrm * xj[f1];
            if (f2 < FF) a2 += nrm * xj[f2];
        }
    }
    float* yr = Yb + (size_t)r * FF;
    yr[lane] = a0;
    yr[f1] = a1;
    if (f2 < FF) yr[f2] = a2;
}

// ---------------- fused: P = relu(Y@M_t + proj_b); logits = P@cls^T + cls_b ----------------
__global__ __launch_bounds__(256) void gemm_fused(const int* __restrict__ meta,
                                                  const int* __restrict__ tile_t, const int* __restrict__ tile_r0,
                                                  const int* __restrict__ perm,
                                                  const float* __restrict__ Yb, const float* __restrict__ M_all,
                                                  const float* __restrict__ proj_b,
                                                  const float* __restrict__ cls_w, const float* __restrict__ cls_b,
                                                  float* __restrict__ out) {
    __shared__ float sm[32 * 167];
    int w = blockIdx.x;
    if (w >= meta[0]) return;
    int t = tile_t[w], r0 = tile_r0[w];
    int tid = threadIdx.x;

    for (int idx = tid; idx < 32 * FF; idx += 256) {
        int row = idx / FF, col = idx - row * FF;
        sm[row * 167 + col] = Yb[(size_t)(r0 + row) * FF + col];
    }
    __syncthreads();

    int rg = tid >> 5;
    int cl = tid & 31;
    const float* M = M_all + (size_t)t * (FF * HH);

    float acc[4][4];
    #pragma unroll
    for (int i = 0; i < 4; ++i)
        #pragma unroll
        for (int jj = 0; jj < 4; ++jj) acc[i][jj] = proj_b[cl + 32 * jj];

    #pragma unroll 2
    for (int k = 0; k < FF; ++k) {
        float y0 = sm[(rg * 4 + 0) * 167 + k];
        float y1 = sm[(rg * 4 + 1) * 167 + k];
        float y2 = sm[(rg * 4 + 2) * 167 + k];
        float y3 = sm[(rg * 4 + 3) * 167 + k];
        const float* mk = M + (size_t)k * HH;
        float m0 = mk[cl];
        float m1 = mk[cl + 32];
        float m2 = mk[cl + 64];
        float m3 = mk[cl + 96];
        acc[0][0] += y0 * m0; acc[0][1] += y0 * m1; acc[0][2] += y0 * m2; acc[0][3] += y0 * m3;
        acc[1][0] += y1 * m0; acc[1][1] += y1 * m1; acc[1][2] += y1 * m2; acc[1][3] += y1 * m3;
        acc[2][0] += y2 * m0; acc[2][1] += y2 * m1; acc[2][2] += y2 * m2; acc[2][3] += y2 * m3;
        acc[3][0] += y3 * m0; acc[3][1] += y3 * m1; acc[3][2] += y3 * m2; acc[3][3] += y3 * m3;
    }
    __syncthreads();

    #pragma unroll
    for (int i = 0; i < 4; ++i)
        #pragma unroll
        for (int jj = 0; jj < 4; ++jj)
            sm[(rg * 4 + i) * 130 + cl + 32 * jj] = fmaxf(acc[i][jj], 0.0f);
    __syncthreads();

    if (tid < 64) {
        int row = tid >> 1, cc = tid & 1;
        const float* pr = sm + row * 130;
        const float* cw = cls_w + cc * HH;
        float s = cls_b[cc];
        #pragma unroll 4
        for (int h = 0; h < HH; ++h) s += pr[h] * cw[h];
        int node = perm[r0 + row];
        if (node >= 0) out[(size_t)node * CC + cc] = s;
    }
}

// ---------------- host ----------------
extern "C" void kernel_launch(void* const* d_in, const int* in_sizes, int n_in,
                              void* d_out, int out_size, void* d_ws, size_t ws_size,
                              hipStream_t stream) {
    const float* x = (const float*)d_in[0];
    const int* ei = (const int*)d_in[1];
    const int* srcp = ei;
    const int* dstp = ei + NE;
    const int* ts = (const int*)d_in[2];
    const float* initial_w = (const float*)d_in[3];
    const float* wih = (const float*)d_in[4];
    const float* whh = (const float*)d_in[5];
    const float* bih = (const float*)d_in[6];
    const float* bhh = (const float*)d_in[7];
    const float* projw = (const float*)d_in[8];
    const float* projb = (const float*)d_in[9];
    const float* clsw = (const float*)d_in[10];
    const float* clsb = (const float*)d_in[11];
    float* out = (float*)d_out;

    char* base = (char*)d_ws;
    size_t o = 0;
    auto alloc = [&](size_t bytes) { size_t r = o; o = (o + bytes + 255) & ~(size_t)255; return r; };

    float*    W_all  = (float*)   (base + alloc((size_t)TT * FF * FF * 4));
    float*    M_all  = (float*)   (base + alloc((size_t)TT * FF * HH * 4));
    _Float16* wkp    = (_Float16*)(base + alloc((size_t)2 * KP * 512 * 2 * 2));
    float*    projwT = (float*)   (base + alloc((size_t)FF * HH * 4));
    int*      off    = (int*)     (base + alloc((size_t)(NN + 1) * 4));
    int*      cursor = (int*)     (base + alloc((size_t)NN * 4));
    int*      adjsrc = (int*)     (base + alloc((size_t)NE * 4));
    float*    degf   = (float*)   (base + alloc((size_t)TT * NN * 4));
    int*      bcnt   = (int*)     (base + alloc((size_t)TT * 4));
    int*      pstart = (int*)     (base + alloc((size_t)(TT + 1) * 4));
    int*      meta   = (int*)     (base + alloc(2 * 4));
    int*      tile_t = (int*)     (base + alloc((size_t)MAXTILES * 4));
    int*      tile_r0= (int*)     (base + alloc((size_t)MAXTILES * 4));
    int*      perm   = (int*)     (base + alloc((size_t)PADN * 4));
    int*      bsum   = (int*)     (base + alloc((size_t)512 * 4));
    int*      bpre   = (int*)     (base + alloc((size_t)520 * 4));
    int*      cnt    = (int*)     (base + alloc((size_t)HB * TT * 4));
    int*      basecol= (int*)     (base + alloc((size_t)HB * TT * 4));
    int*      rank   = (int*)     (base + alloc((size_t)NN * 4));
    float*    Yb     = (float*)   (base + alloc((size_t)PADN * FF * 4));

    hipMemsetAsync(off, 0, (size_t)(NN + 1) * 4, stream);
    hipMemsetAsync(cursor, 0, (size_t)NN * 4, stream);
    hipMemsetAsync(perm, 0xFF, (size_t)PADN * 4, stream);

    prep_pack<<<420, 256, 0, stream>>>(wih, whh, projw, wkp, projwT);
    count_indeg<<<(NE + 255) / 256, 256, 0, stream>>>(dstp, off);
    hist_rank<<<HB, 256, 0, stream>>>(ts, cnt, rank);
    scan_p1<<<SNB, 256, 0, stream>>>(off, bsum);
    scan_p2<<<1, 512, 0, stream>>>(bsum, bpre, off);
    scan_p3<<<SNB, 512, 0, stream>>>(off, bpre);
    fill_adj<<<(NE + 255) / 256, 256, 0, stream>>>(srcp, dstp, off, cursor, adjsrc);
    degf_hist<<<(NN + 255) / 256, 256, 0, stream>>>(off, adjsrc, ts, degf);
    bucket_scan<<<TT, 256, 0, stream>>>(cnt, basecol, bcnt);
    make_tiles<<<1, 64, 0, stream>>>(bcnt, pstart, tile_t, tile_r0, meta);
    perm_scatter<<<HB, 256, 0, stream>>>(ts, rank, basecol, pstart, perm);

    gru_evolve<<<FF, 1024, 0, stream>>>(initial_w, wkp, bih, bhh, W_all);
    m_build<<<TT * 21, 1024, 0, stream>>>(W_all, projwT, M_all);

    ybuild<<<PADN / 4, 256, 0, stream>>>(perm, ts, x, off, adjsrc, degf, Yb);

    gemm_fused<<<MAXTILES, 256, 0, stream>>>(meta, tile_t, tile_r0, perm, Yb, M_all,
                                             projb, clsw, clsb, out);
}

// Round 6
// 515.542 us; speedup vs baseline: 5.5087x; 1.2843x over previous
//
#include <hip/hip_runtime.h>
#include <hip/hip_fp16.h>
#include <math.h>

#define NN 200000
#define NE 500000
#define FF 166
#define HH 128
#define CC 2
#define TT 49
#define GG 498            // 3*FF
#define PADN 203136
#define MAXTILES 6400
#define KP 84             // k-pairs (166 -> 84 half2, padded)
#define KPAD 192          // K padded to 6*32 for MFMA
#define SCB 512           // scan elements per block
#define SNB 391           // ceil(NN/512)
#define HB 782            // ceil(NN/256) histogram blocks

typedef _Float16 half2v __attribute__((ext_vector_type(2)));
typedef _Float16 f16x8 __attribute__((ext_vector_type(8)));
typedef float f32x4 __attribute__((ext_vector_type(4)));

static __device__ __forceinline__ float fdot2f(half2v a, half2v b, float c) {
#if __has_builtin(__builtin_amdgcn_fdot2)
    return __builtin_amdgcn_fdot2(a, b, c, false);
#else
    return c + (float)a.x * (float)b.x + (float)a.y * (float)b.y;
#endif
}

// ---------------- prep: pack GRU weights as [m][kp][512] half2 (k-pairs), fp32 projT ----------------
__global__ void prep_pack(const float* __restrict__ wih, const float* __restrict__ whh,
                          const float* __restrict__ projw,
                          _Float16* __restrict__ wkp, float* __restrict__ projwT) {
    int idx = blockIdx.x * 256 + threadIdx.x;
    const int A = 2 * KP * 512; // 86016 half2 slots
    if (idx < A) {
        int m = idx / (KP * 512);
        int r = idx - m * (KP * 512);
        int kp = r >> 9, c = r & 511;
        const float* Wm = m ? whh : wih;
        float x0 = 0.0f, x1 = 0.0f;
        if (c < GG) {
            int k0 = 2 * kp, k1 = 2 * kp + 1;
            if (k0 < FF) x0 = Wm[c * FF + k0];
            if (k1 < FF) x1 = Wm[c * FF + k1];
        }
        wkp[2 * idx]     = (_Float16)x0;
        wkp[2 * idx + 1] = (_Float16)x1;
    } else if (idx < A + FF * HH) {
        int q = idx - A;
        int k = q >> 7, h = q & 127;
        projwT[q] = projw[h * FF + k];
    }
}

// ---------------- CSR build ----------------
__global__ void count_indeg(const int* __restrict__ dst, int* __restrict__ off) {
    int e = blockIdx.x * 256 + threadIdx.x;
    if (e < NE) atomicAdd(&off[dst[e]], 1);
}

// ---- 3-phase multi-block exclusive scan of off[0..NN) ----
__global__ __launch_bounds__(256) void scan_p1(const int* __restrict__ off, int* __restrict__ bsum) {
    __shared__ int s[256];
    int b = blockIdx.x, tid = threadIdx.x;
    int i0 = b * SCB + tid * 2;
    int v = 0;
    if (i0 < NN) v += off[i0];
    if (i0 + 1 < NN) v += off[i0 + 1];
    s[tid] = v;
    __syncthreads();
    for (int d = 128; d > 0; d >>= 1) {
        if (tid < d) s[tid] += s[tid + d];
        __syncthreads();
    }
    if (tid == 0) bsum[b] = s[0];
}

__global__ __launch_bounds__(512) void scan_p2(const int* __restrict__ bsum, int* __restrict__ bpre,
                                               int* __restrict__ off) {
    __shared__ int s[512];
    int tid = threadIdx.x;
    int v = (tid < SNB) ? bsum[tid] : 0;
    s[tid] = v;
    __syncthreads();
    for (int d = 1; d < 512; d <<= 1) {
        int u = (tid >= d) ? s[tid - d] : 0;
        __syncthreads();
        s[tid] += u;
        __syncthreads();
    }
    bpre[tid] = s[tid] - v;  // exclusive
    if (tid == 511) off[NN] = s[511];  // total edges
}

__global__ __launch_bounds__(512) void scan_p3(int* __restrict__ off, const int* __restrict__ bpre) {
    __shared__ int s[512];
    int b = blockIdx.x, tid = threadIdx.x;
    int i = b * SCB + tid;
    int v = (i < NN) ? off[i] : 0;
    s[tid] = v;
    __syncthreads();
    for (int d = 1; d < 512; d <<= 1) {
        int u = (tid >= d) ? s[tid - d] : 0;
        __syncthreads();
        s[tid] += u;
        __syncthreads();
    }
    if (i < NN) off[i] = s[tid] - v + bpre[b];
}

__global__ void fill_adj(const int* __restrict__ src, const int* __restrict__ dst,
                         const int* __restrict__ off, int* __restrict__ cursor,
                         int* __restrict__ adjsrc) {
    int e = blockIdx.x * 256 + threadIdx.x;
    if (e < NE) {
        int d = dst[e];
        int p = atomicAdd(&cursor[d], 1);
        adjsrc[off[d] + p] = src[e];
    }
}

// degf[t][i] = 1 + #{in-edges (j->i) : ts[j] <= t}; one histogram pass per node
__global__ __launch_bounds__(256) void degf_hist(const int* __restrict__ off, const int* __restrict__ adjsrc,
                                                 const int* __restrict__ ts, float* __restrict__ degf) {
    __shared__ unsigned short sh[TT * 256];
    int tid = threadIdx.x;
    int i = blockIdx.x * 256 + tid;
    for (int t = 0; t < TT; ++t) sh[t * 256 + tid] = 0;
    if (i >= NN) return;
    int e0 = off[i], e1 = off[i + 1];
    for (int e = e0; e < e1; ++e) {
        int tj = ts[adjsrc[e]];
        sh[tj * 256 + tid]++;
    }
    int cum = 1;
    for (int t = 0; t < TT; ++t) {
        cum += sh[t * 256 + tid];
        degf[(size_t)t * NN + i] = (float)cum;
    }
}

// ---------------- counting sort of nodes by time bucket (no global atomics) ----------------
__global__ __launch_bounds__(256) void hist_rank(const int* __restrict__ ts,
                                                 int* __restrict__ cnt, int* __restrict__ rank) {
    __shared__ int h[TT];
    int tid = threadIdx.x, b = blockIdx.x;
    if (tid < TT) h[tid] = 0;
    __syncthreads();
    int i = b * 256 + tid;
    if (i < NN) {
        int t = ts[i];
        rank[i] = atomicAdd(&h[t], 1);   // LDS atomic: cheap
    }
    __syncthreads();
    if (tid < TT) cnt[b * TT + tid] = h[tid];
}

__global__ __launch_bounds__(256) void bucket_scan(const int* __restrict__ cnt,
                                                   int* __restrict__ basecol, int* __restrict__ bcnt) {
    __shared__ int s[256];
    int t = blockIdx.x, tid = threadIdx.x;
    const int CH = (HB + 255) / 256; // 4
    int b0 = tid * CH;
    int loc[CH];
    int sum = 0;
    for (int u = 0; u < CH; ++u) {
        int b = b0 + u;
        int v = (b < HB) ? cnt[b * TT + t] : 0;
        loc[u] = sum;
        sum += v;
    }
    s[tid] = sum;
    __syncthreads();
    for (int d = 1; d < 256; d <<= 1) {
        int u = (tid >= d) ? s[tid - d] : 0;
        __syncthreads();
        s[tid] += u;
        __syncthreads();
    }
    int base = s[tid] - sum;   // exclusive prefix for this thread's chunk
    for (int u = 0; u < CH; ++u) {
        int b = b0 + u;
        if (b < HB) basecol[b * TT + t] = base + loc[u];
    }
    if (tid == 255) bcnt[t] = s[255];
}

__global__ __launch_bounds__(256) void perm_scatter(const int* __restrict__ ts, const int* __restrict__ rank,
                                                    const int* __restrict__ basecol, const int* __restrict__ pstart,
                                                    int* __restrict__ perm) {
    int b = blockIdx.x;
    int i = b * 256 + threadIdx.x;
    if (i < NN) {
        int t = ts[i];
        perm[pstart[t] + basecol[b * TT + t] + rank[i]] = i;
    }
}

// ---------------- bucket / tile tables (32-row tiles) ----------------
__global__ void make_tiles(const int* __restrict__ bcnt, int* __restrict__ pstart,
                           int* __restrict__ tile_t, int* __restrict__ tile_r0,
                           int* __restrict__ meta) {
    __shared__ int s_nt[64];
    int t = threadIdx.x; // 64 threads
    int nt = (t < TT) ? (bcnt[t] + 31) / 32 : 0;
    s_nt[t] = nt;
    __syncthreads();
    for (int d = 1; d < 64; d <<= 1) {
        int v = (t >= d) ? s_nt[t - d] : 0;
        __syncthreads();
        s_nt[t] += v;
        __syncthreads();
    }
    int ntbase = s_nt[t] - nt;
    int pbase = ntbase * 32;
    if (t < TT) {
        pstart[t] = pbase;
        for (int u = 0; u < nt; ++u) {
            tile_t[ntbase + u] = t;
            tile_r0[ntbase + u] = pbase + u * 32;
        }
    }
    if (t == 63) {
        meta[0] = s_nt[63];
        meta[1] = s_nt[63] * 32;
        pstart[TT] = s_nt[63] * 32;
    }
}

// ---------------- GRU chain: 1 row/block, thread=(matrix m, gate col c), dot2 inner ----------------
__global__ __launch_bounds__(1024) void gru_evolve(
        const float* __restrict__ initial_w,
        const _Float16* __restrict__ wkp,      // [2][KP][512] half2
        const float* __restrict__ bih, const float* __restrict__ bhh,
        float* __restrict__ W_all) {
    __shared__ float s_w[FF];
    __shared__ __align__(8) _Float16 s_wh[2 * KP];   // 168, padded with zeros
    __shared__ float s_pre[2][512];
    int tid = threadIdx.x;
    int row = blockIdx.x;

    if (tid < FF) {
        float v = initial_w[(size_t)row * FF + tid];
        s_w[tid] = v;
        s_wh[tid] = (_Float16)v;
    } else if (tid < 2 * KP) {
        s_wh[tid] = (_Float16)0.0f;
    }

    int m = (tid >= 498) ? 1 : 0;
    int c = tid - m * 498;
    bool act = tid < 996;
    const half2v* __restrict__ pW = (const half2v*)wkp + (size_t)m * KP * 512 + (act ? c : 0);
    const half2v* s_wh2 = (const half2v*)s_wh;

    float bi_r = 0, bi_z = 0, bi_n = 0, bh_r = 0, bh_z = 0, bh_n = 0;
    if (tid < FF) {
        bi_r = bih[tid]; bi_z = bih[FF + tid]; bi_n = bih[2 * FF + tid];
        bh_r = bhh[tid]; bh_z = bhh[FF + tid]; bh_n = bhh[2 * FF + tid];
    }
    __syncthreads();

    for (int t = 0; t < TT; ++t) {
        if (act) {
            float acc = 0.0f;
            #pragma unroll 4
            for (int kp = 0; kp < KP; ++kp) {
                half2v w2 = s_wh2[kp];
                half2v g2 = pW[(size_t)kp << 9];
                acc = fdot2f(g2, w2, acc);
            }
            s_pre[m][c] = acc;
        }
        __syncthreads();
        if (tid < FF) {
            float i_r = s_pre[0][tid]          + bi_r;
            float h_r = s_pre[1][tid]          + bh_r;
            float i_z = s_pre[0][FF + tid]     + bi_z;
            float h_z = s_pre[1][FF + tid]     + bh_z;
            float i_n = s_pre[0][2 * FF + tid] + bi_n;
            float h_n = s_pre[1][2 * FF + tid] + bh_n;
            float rg = 1.0f / (1.0f + expf(-(i_r + h_r)));
            float zg = 1.0f / (1.0f + expf(-(i_z + h_z)));
            float ng = tanhf(i_n + rg * h_n);
            float wnew = (1.0f - zg) * ng + zg * s_w[tid];
            s_w[tid] = wnew;
            s_wh[tid] = (_Float16)wnew;
            W_all[((size_t)t * FF + row) * FF + tid] = wnew;
        }
        __syncthreads();
    }
}

// ---------------- Mh[t][h][k] (fp16, k padded to 192) = W_t @ projw^T transposed ----------------
__global__ __launch_bounds__(1024) void m_build(const float* __restrict__ W_all,
                                                const float* __restrict__ projwT,
                                                _Float16* __restrict__ Mh) {
    __shared__ __align__(16) float sw[8][168];
    int blk = blockIdx.x;
    int t = blk / 24, rb = blk - t * 24;
    int tid = threadIdx.x;
    int r0 = rb * 8;
    for (int idx = tid; idx < 8 * FF; idx += 1024) {
        int rr = idx / FF, k = idx - rr * FF;
        int r = r0 + rr;
        sw[rr][k] = (r < FF) ? W_all[((size_t)t * FF + r) * FF + k] : 0.0f;
    }
    __syncthreads();
    int rr = tid >> 7, h = tid & 127;
    int r = r0 + rr;
    if (r >= KPAD) return;
    float acc = 0.0f;
    if (r < FF) {
        const float* __restrict__ pw = projwT + h;
        #pragma unroll 4
        for (int c4 = 0; c4 < 164; c4 += 4) {
            float4 w = *(const float4*)&sw[rr][c4];
            acc += w.x * pw[(size_t)(c4 + 0) << 7];
            acc += w.y * pw[(size_t)(c4 + 1) << 7];
            acc += w.z * pw[(size_t)(c4 + 2) << 7];
            acc += w.w * pw[(size_t)(c4 + 3) << 7];
        }
        acc += sw[rr][164] * pw[(size_t)164 << 7];
        acc += sw[rr][165] * pw[(size_t)165 << 7];
    }
    Mh[((size_t)t * HH + h) * KPAD + r] = (_Float16)acc;
}

// ---------------- y build: y_i = x_i/deg_i + sum norm_ij x_j -> fp16 [r][192] ----------------
__global__ __launch_bounds__(256) void ybuild(const int* __restrict__ perm, const int* __restrict__ ts,
                                              const float* __restrict__ x,
                                              const int* __restrict__ off, const int* __restrict__ adjsrc,
                                              const float* __restrict__ degf, _Float16* __restrict__ Yh) {
    int r = blockIdx.x * 4 + (threadIdx.x >> 6);
    int lane = threadIdx.x & 63;
    int i = perm[r];
    _Float16* yr = Yh + (size_t)r * KPAD;
    if (i < 0) {
        yr[lane] = (_Float16)0.0f;
        yr[lane + 64] = (_Float16)0.0f;
        yr[lane + 128] = (_Float16)0.0f;
        return;
    }
    int t = ts[i];
    const float* degt = degf + (size_t)t * NN;
    float degi = degt[i];
    float inv_degi = 1.0f / degi;
    float dinv_i = rsqrtf(degi);
    int f1 = lane + 64, f2 = lane + 128;
    const float* xi = x + (size_t)i * FF;
    float a0 = xi[lane] * inv_degi;
    float a1 = xi[f1] * inv_degi;
    float a2 = (f2 < FF) ? xi[f2] * inv_degi : 0.0f;
    int e0 = off[i], e1 = off[i + 1];
    for (int e = e0; e < e1; ++e) {
        int j = adjsrc[e];
        if (ts[j] <= t) {
            float nrm = rsqrtf(degt[j]) * dinv_i;
            const float* xj = x + (size_t)j * FF;
            a0 += nrm * xj[lane];
            a1 += nrm * xj[f1];
            if (f2 < FF) a2 += nrm * xj[f2];
        }
    }
    yr[lane] = (_Float16)a0;
    yr[f1] = (_Float16)a1;
    yr[f2] = (f2 < FF) ? (_Float16)a2 : (_Float16)0.0f;
}

// ---------------- MFMA: P = relu(Y@M_t + pb); logits = P@cls^T + cb ----------------
__global__ __launch_bounds__(256) void gemm_mfma(
        const int* __restrict__ meta, const int* __restrict__ tile_t,
        const int* __restrict__ tile_r0, const int* __restrict__ perm,
        const _Float16* __restrict__ Yh, const _Float16* __restrict__ Mh,
        const float* __restrict__ proj_b, const float* __restrict__ cls_w,
        const float* __restrict__ cls_b, float* __restrict__ out) {
    __shared__ __align__(16) char smraw[32 * 130 * 4];   // 16640 B; Y stage needs 12800
    _Float16* sY = (_Float16*)smraw;   // [32][200] fp16
    float* sP = (float*)smraw;         // [32][130] f32
    int bid = blockIdx.x;
    if (bid >= meta[0]) return;
    int t = tile_t[bid], r0 = tile_r0[bid];
    int tid = threadIdx.x;

    // stage Y tile: 32 rows x 192 fp16 (LDS stride 200 -> only 2-way conflicts)
    {
        const uint4* src = (const uint4*)(Yh + (size_t)r0 * KPAD);
        #pragma unroll
        for (int u = 0; u < 3; ++u) {
            int q = tid + u * 256;          // 0..767
            int row = q / 24, kc = q - row * 24;
            *(uint4*)(sY + row * 200 + kc * 8) = src[row * 24 + kc];
        }
    }
    __syncthreads();

    int lane = tid & 63;
    int w = tid >> 6;          // wave 0..3 -> cols w*32..w*32+31
    int lr = lane & 15;
    int kg = lane >> 4;

    f32x4 acc00 = {0,0,0,0}, acc01 = {0,0,0,0}, acc10 = {0,0,0,0}, acc11 = {0,0,0,0};
    const _Float16* B0 = Mh + ((size_t)t * HH + w * 32 + lr) * KPAD + kg * 8;
    const _Float16* B1 = B0 + 16 * KPAD;
    const _Float16* A0 = sY + lr * 200 + kg * 8;
    const _Float16* A1 = A0 + 16 * 200;

    #pragma unroll
    for (int s = 0; s < 6; ++s) {
        f16x8 a0 = *(const f16x8*)(A0 + s * 32);
        f16x8 a1 = *(const f16x8*)(A1 + s * 32);
        f16x8 b0 = *(const f16x8*)(B0 + s * 32);
        f16x8 b1 = *(const f16x8*)(B1 + s * 32);
        acc00 = __builtin_amdgcn_mfma_f32_16x16x32_f16(a0, b0, acc00, 0, 0, 0);
        acc01 = __builtin_amdgcn_mfma_f32_16x16x32_f16(a0, b1, acc01, 0, 0, 0);
        acc10 = __builtin_amdgcn_mfma_f32_16x16x32_f16(a1, b0, acc10, 0, 0, 0);
        acc11 = __builtin_amdgcn_mfma_f32_16x16x32_f16(a1, b1, acc11, 0, 0, 0);
    }

    float pb0 = proj_b[w * 32 + lr];
    float pb1 = proj_b[w * 32 + 16 + lr];
    __syncthreads();   // K-loop LDS reads finished; reuse as sP
    int prow = kg * 4;
    int col0 = w * 32 + lr;
    #pragma unroll
    for (int r = 0; r < 4; ++r) {
        sP[(prow + r) * 130 + col0]           = fmaxf(acc00[r] + pb0, 0.0f);
        sP[(prow + r) * 130 + col0 + 16]      = fmaxf(acc01[r] + pb1, 0.0f);
        sP[(16 + prow + r) * 130 + col0]      = fmaxf(acc10[r] + pb0, 0.0f);
        sP[(16 + prow + r) * 130 + col0 + 16] = fmaxf(acc11[r] + pb1, 0.0f);
    }
    __syncthreads();

    // logits: thread = row(32) x cc(2) x quarter(4); shuffle-reduce the quarters
    int row = tid >> 3, cc = (tid >> 2) & 1, q = tid & 3;
    const float* pr = sP + row * 130 + q * 32;
    const float* cw = cls_w + cc * HH + q * 32;
    float s = 0.0f;
    #pragma unroll 8
    for (int h = 0; h < 32; ++h) s += pr[h] * cw[h];
    s += __shfl_xor(s, 1);
    s += __shfl_xor(s, 2);
    if (q == 0) {
        int node = perm[r0 + row];
        if (node >= 0) out[(size_t)node * CC + cc] = s + cls_b[cc];
    }
}

// ---------------- host ----------------
extern "C" void kernel_launch(void* const* d_in, const int* in_sizes, int n_in,
                              void* d_out, int out_size, void* d_ws, size_t ws_size,
                              hipStream_t stream) {
    const float* x = (const float*)d_in[0];
    const int* ei = (const int*)d_in[1];
    const int* srcp = ei;
    const int* dstp = ei + NE;
    const int* ts = (const int*)d_in[2];
    const float* initial_w = (const float*)d_in[3];
    const float* wih = (const float*)d_in[4];
    const float* whh = (const float*)d_in[5];
    const float* bih = (const float*)d_in[6];
    const float* bhh = (const float*)d_in[7];
    const float* projw = (const float*)d_in[8];
    const float* projb = (const float*)d_in[9];
    const float* clsw = (const float*)d_in[10];
    const float* clsb = (const float*)d_in[11];
    float* out = (float*)d_out;

    char* base = (char*)d_ws;
    size_t o = 0;
    auto alloc = [&](size_t bytes) { size_t r = o; o = (o + bytes + 255) & ~(size_t)255; return r; };

    float*    W_all  = (float*)   (base + alloc((size_t)TT * FF * FF * 4));
    _Float16* Mh     = (_Float16*)(base + alloc((size_t)TT * HH * KPAD * 2));
    _Float16* wkp    = (_Float16*)(base + alloc((size_t)2 * KP * 512 * 2 * 2));
    float*    projwT = (float*)   (base + alloc((size_t)FF * HH * 4));
    int*      off    = (int*)     (base + alloc((size_t)(NN + 1) * 4));
    int*      cursor = (int*)     (base + alloc((size_t)NN * 4));
    int*      adjsrc = (int*)     (base + alloc((size_t)NE * 4));
    float*    degf   = (float*)   (base + alloc((size_t)TT * NN * 4));
    int*      bcnt   = (int*)     (base + alloc((size_t)TT * 4));
    int*      pstart = (int*)     (base + alloc((size_t)(TT + 1) * 4));
    int*      meta   = (int*)     (base + alloc(2 * 4));
    int*      tile_t = (int*)     (base + alloc((size_t)MAXTILES * 4));
    int*      tile_r0= (int*)     (base + alloc((size_t)MAXTILES * 4));
    int*      perm   = (int*)     (base + alloc((size_t)PADN * 4));
    int*      bsum   = (int*)     (base + alloc((size_t)512 * 4));
    int*      bpre   = (int*)     (base + alloc((size_t)520 * 4));
    int*      cnt    = (int*)     (base + alloc((size_t)HB * TT * 4));
    int*      basecol= (int*)     (base + alloc((size_t)HB * TT * 4));
    int*      rank   = (int*)     (base + alloc((size_t)NN * 4));
    _Float16* Yh     = (_Float16*)(base + alloc((size_t)PADN * KPAD * 2));

    hipMemsetAsync(off, 0, (size_t)(NN + 1) * 4, stream);
    hipMemsetAsync(cursor, 0, (size_t)NN * 4, stream);
    hipMemsetAsync(perm, 0xFF, (size_t)PADN * 4, stream);

    prep_pack<<<420, 256, 0, stream>>>(wih, whh, projw, wkp, projwT);
    count_indeg<<<(NE + 255) / 256, 256, 0, stream>>>(dstp, off);
    hist_rank<<<HB, 256, 0, stream>>>(ts, cnt, rank);
    scan_p1<<<SNB, 256, 0, stream>>>(off, bsum);
    scan_p2<<<1, 512, 0, stream>>>(bsum, bpre, off);
    scan_p3<<<SNB, 512, 0, stream>>>(off, bpre);
    fill_adj<<<(NE + 255) / 256, 256, 0, stream>>>(srcp, dstp, off, cursor, adjsrc);
    degf_hist<<<(NN + 255) / 256, 256, 0, stream>>>(off, adjsrc, ts, degf);
    bucket_scan<<<TT, 256, 0, stream>>>(cnt, basecol, bcnt);
    make_tiles<<<1, 64, 0, stream>>>(bcnt, pstart, tile_t, tile_r0, meta);
    perm_scatter<<<HB, 256, 0, stream>>>(ts, rank, basecol, pstart, perm);

    gru_evolve<<<FF, 1024, 0, stream>>>(initial_w, wkp, bih, bhh, W_all);
    m_build<<<TT * 24, 1024, 0, stream>>>(W_all, projwT, Mh);

    ybuild<<<PADN / 4, 256, 0, stream>>>(perm, ts, x, off, adjsrc, degf, Yh);

    gemm_mfma<<<MAXTILES, 256, 0, stream>>>(meta, tile_t, tile_r0, perm, Yh, Mh,
                                            projb, clsw, clsb, out);
}